// Round 5
// baseline (864.121 us; speedup 1.0000x reference)
//
#include <hip/hip_runtime.h>

#define NB 128   // batch
#define NS 128   // context seq len
#define NT 12    // target seq len
#define NE 300   // embed dim
#define NH 512   // hidden
#define NCOL 2048  // 4*NH
#define NBLK 256

typedef _Float16 h8v __attribute__((ext_vector_type(8)));
typedef __attribute__((ext_vector_type(4))) float f4v;
typedef __attribute__((ext_vector_type(4))) int   i4v;

__device__ __forceinline__ unsigned short f2h(float f) {
  union { _Float16 h; unsigned short u; } c; c.h = (_Float16)f; return c.u;
}
__device__ __forceinline__ float sigm(float x) { return 1.f / (1.f + __expf(-x)); }
__device__ __forceinline__ float tanh_(float x) { const float e = __expf(2.f * x); return 1.f - 2.f / (e + 1.f); }

// ---- cross-CU exchange primitives ----
// fast (group co-resident on ONE XCD, runtime-verified): plain stores -> local
// L2 (L1 is write-through); loads with sc0 (= legacy GLC: L1-bypass, L2-hit).
// slow (any placement): sc1 = bypass L1+L2, coherence point = Infinity Fabric.
__device__ __forceinline__ void st16h(unsigned short* p, unsigned short v, bool fast) {
  unsigned vv = v;
  if (fast) asm volatile("global_store_short %0, %1, off"     :: "v"(p), "v"(vv) : "memory");
  else      asm volatile("global_store_short %0, %1, off sc1" :: "v"(p), "v"(vv) : "memory");
}
__device__ __forceinline__ void st32f_uc(float* p, float v) {
  asm volatile("global_store_dword %0, %1, off sc1" :: "v"(p), "v"(v) : "memory");
}
__device__ __forceinline__ void st32i_uc(int* p, int v) {
  asm volatile("global_store_dword %0, %1, off sc1" :: "v"(p), "v"(v) : "memory");
}
__device__ __forceinline__ int ldflag(const int* p, bool fast) {
  int v;
  if (fast) asm volatile("global_load_dword %0, %1, off sc0\n\ts_waitcnt vmcnt(0)" : "=v"(v) : "v"(p) : "memory");
  else      asm volatile("global_load_dword %0, %1, off sc1\n\ts_waitcnt vmcnt(0)" : "=v"(v) : "v"(p) : "memory");
  return v;
}
// 16 x 16B loads of one hbuf row at offsets 0,64,...,960 (one vmcnt at end)
__device__ __forceinline__ void ld16h(const char* a, i4v* r, bool fast) {
  if (fast) {
    asm volatile(
      "global_load_dwordx4 %0, %16, off sc0\n\t"
      "global_load_dwordx4 %1, %16, off offset:64 sc0\n\t"
      "global_load_dwordx4 %2, %16, off offset:128 sc0\n\t"
      "global_load_dwordx4 %3, %16, off offset:192 sc0\n\t"
      "global_load_dwordx4 %4, %16, off offset:256 sc0\n\t"
      "global_load_dwordx4 %5, %16, off offset:320 sc0\n\t"
      "global_load_dwordx4 %6, %16, off offset:384 sc0\n\t"
      "global_load_dwordx4 %7, %16, off offset:448 sc0\n\t"
      "global_load_dwordx4 %8, %16, off offset:512 sc0\n\t"
      "global_load_dwordx4 %9, %16, off offset:576 sc0\n\t"
      "global_load_dwordx4 %10, %16, off offset:640 sc0\n\t"
      "global_load_dwordx4 %11, %16, off offset:704 sc0\n\t"
      "global_load_dwordx4 %12, %16, off offset:768 sc0\n\t"
      "global_load_dwordx4 %13, %16, off offset:832 sc0\n\t"
      "global_load_dwordx4 %14, %16, off offset:896 sc0\n\t"
      "global_load_dwordx4 %15, %16, off offset:960 sc0\n\t"
      "s_waitcnt vmcnt(0)"
      : "=&v"(r[0]), "=&v"(r[1]), "=&v"(r[2]), "=&v"(r[3]),
        "=&v"(r[4]), "=&v"(r[5]), "=&v"(r[6]), "=&v"(r[7]),
        "=&v"(r[8]), "=&v"(r[9]), "=&v"(r[10]), "=&v"(r[11]),
        "=&v"(r[12]), "=&v"(r[13]), "=&v"(r[14]), "=&v"(r[15])
      : "v"(a) : "memory");
  } else {
    asm volatile(
      "global_load_dwordx4 %0, %16, off sc1\n\t"
      "global_load_dwordx4 %1, %16, off offset:64 sc1\n\t"
      "global_load_dwordx4 %2, %16, off offset:128 sc1\n\t"
      "global_load_dwordx4 %3, %16, off offset:192 sc1\n\t"
      "global_load_dwordx4 %4, %16, off offset:256 sc1\n\t"
      "global_load_dwordx4 %5, %16, off offset:320 sc1\n\t"
      "global_load_dwordx4 %6, %16, off offset:384 sc1\n\t"
      "global_load_dwordx4 %7, %16, off offset:448 sc1\n\t"
      "global_load_dwordx4 %8, %16, off offset:512 sc1\n\t"
      "global_load_dwordx4 %9, %16, off offset:576 sc1\n\t"
      "global_load_dwordx4 %10, %16, off offset:640 sc1\n\t"
      "global_load_dwordx4 %11, %16, off offset:704 sc1\n\t"
      "global_load_dwordx4 %12, %16, off offset:768 sc1\n\t"
      "global_load_dwordx4 %13, %16, off offset:832 sc1\n\t"
      "global_load_dwordx4 %14, %16, off offset:896 sc1\n\t"
      "global_load_dwordx4 %15, %16, off offset:960 sc1\n\t"
      "s_waitcnt vmcnt(0)"
      : "=&v"(r[0]), "=&v"(r[1]), "=&v"(r[2]), "=&v"(r[3]),
        "=&v"(r[4]), "=&v"(r[5]), "=&v"(r[6]), "=&v"(r[7]),
        "=&v"(r[8]), "=&v"(r[9]), "=&v"(r[10]), "=&v"(r[11]),
        "=&v"(r[12]), "=&v"(r[13]), "=&v"(r[14]), "=&v"(r[15])
      : "v"(a) : "memory");
  }
}

struct Params {
  const int *tids, *tlen, *lids, *llen, *rids, *rlen;
  const float *emb, *Wl, *bl, *Wr, *br, *Wd, *bd;
  float* out;
  unsigned short* hbuf;  // [2(pp)][2(side)][NB][NH] f16 ping-pong
  float* hfin;           // [2(side)][NB][NH] fp32 (always sc1)
  int* bar;              // flags: [8 groups][32 slots]
  int* xids;             // [8 groups][32 slots] XCC ids
};

// release: every wave drains its stores, block-sync, lane0 publishes epoch
__device__ __forceinline__ void grel(int* fl, int slot, int val, bool fast) {
  asm volatile("s_waitcnt vmcnt(0)" ::: "memory");
  __syncthreads();
  if (threadIdx.x == 0) {
    if (fast) asm volatile("global_store_dword %0, %1, off"     :: "v"(fl + slot), "v"(val) : "memory");
    else      asm volatile("global_store_dword %0, %1, off sc1" :: "v"(fl + slot), "v"(val) : "memory");
  }
}
// wait: every wave polls all 32 slots independently (no block sync needed)
__device__ __forceinline__ void gwait(const int* fl, int target, bool fast) {
  const int* f = fl + (threadIdx.x & 31);
  int v = ldflag(f, fast);
  while (__ballot(v < target) != 0ull) {
    __builtin_amdgcn_s_sleep(1);
    v = ldflag(f, fast);
  }
}

__global__ __launch_bounds__(256, 1) void lstm_all(Params p) {
  // LDS map: xS = lds+32768 (32 rows x 640B f16, XOR-swizzled)
  //          zS = lds+53248 (32x64 float)
  //          prologue: meanTT/wT alias lds+0
  __shared__ __align__(16) char lds[61440];
  __shared__ int lenL[32];
  __shared__ float redL[16];

  const int tid = threadIdx.x;
  const int wid = blockIdx.x;

  const int bt = wid & 3, side = (wid >> 2) & 1, ht = wid >> 3;
  const int b0 = bt * 32, d0c = ht * 16;
  const int* lenp = side ? p.rlen : p.llen;
  const int* gids = side ? p.rids : p.lids;
  const float* W = side ? p.Wr : p.Wl;
  const float* bias = side ? p.br : p.bl;
  const int g = side * 4 + bt;
  int* fl = p.bar + g * 32;

  // ---- publish own XCC id (detection completes after prologue) ----
  int myxcc;
  asm volatile("s_getreg_b32 %0, hwreg(HW_REG_XCC_ID)" : "=s"(myxcc));
  if (tid == 0) st32i_uc(&p.xids[g * 32 + ht], myxcc);
  grel(fl, ht, 1, false);

  float* meanTT = (float*)lds;
  unsigned short* wT = (unsigned short*)lds;
  float* zS = (float*)(lds + 53248);

  // ---------------- phase 1: mean_t (fp32, transposed [k][r]) ----------------
  {
    const int r = tid >> 3, l8 = tid & 7;
    const int b = b0 + r;
    const int Lt = p.tlen[b];
    const float inv = 1.f / (float)Lt;
    int toks[NT];
    #pragma unroll
    for (int t = 0; t < NT; ++t) toks[t] = p.tids[b * NT + t];
    for (int k = l8; k < NE; k += 8) {
      float s = 0.f;
      #pragma unroll
      for (int t = 0; t < NT; ++t)
        if (t < Lt) s += p.emb[(size_t)toks[t] * NE + k];
      meanTT[k * 32 + r] = s * inv;
    }
    if (tid < 32) lenL[tid] = lenp[b0 + tid];
  }
  __syncthreads();

  // ---------------- phase 2: z_base = bias + mean @ W[300:600] ----------------
  const int dloc = tid & 15;
  const int r1 = tid >> 4;   // 0..15
  const int r2 = r1 + 16;
  float zb1[4], zb2[4];
  {
    const int c = tid & 63, rq = tid >> 6;
    const int gcol = (c >> 4) * NH + d0c + (c & 15);
    float acc[8];
    #pragma unroll
    for (int i = 0; i < 8; ++i) acc[i] = 0.f;
    const float* wp = W + (size_t)NE * NCOL + gcol;
    for (int k = 0; k < NE; ++k) {
      const float wv = wp[(size_t)k * NCOL];
      const f4v m0 = *(const f4v*)(meanTT + k * 32 + rq * 8);
      const f4v m1 = *(const f4v*)(meanTT + k * 32 + rq * 8 + 4);
      acc[0] += m0[0] * wv; acc[1] += m0[1] * wv; acc[2] += m0[2] * wv; acc[3] += m0[3] * wv;
      acc[4] += m1[0] * wv; acc[5] += m1[1] * wv; acc[6] += m1[2] * wv; acc[7] += m1[3] * wv;
    }
    #pragma unroll
    for (int rr = 0; rr < 8; ++rr) zS[(rq * 8 + rr) * 64 + c] = acc[rr];
  }
  __syncthreads();
  #pragma unroll
  for (int gq = 0; gq < 4; ++gq) {
    zb1[gq] = zS[r1 * 64 + gq * 16 + dloc] + bias[gq * NH + d0c + dloc];
    zb2[gq] = zS[r2 * 64 + gq * 16 + dloc] + bias[gq * NH + d0c + dloc];
  }
  __syncthreads();

  // ---------------- phase 3: W -> register B-fragments (f16) ----------------
  const int wv_ = tid >> 6;
  const int ln  = tid & 63;
  const int mt  = wv_ & 1;
  const int gp  = (wv_ >> 1) * 2;
  const int kgrp = ln >> 4;
  h8v bfr[2][26];
  {
    const int r3 = tid >> 3, part = tid & 7, s3 = part >> 1, hf = part & 1;
    for (int kt = 0; kt < 26; ++kt) {
      const int k = (kt < 10) ? (kt * 32 + r3) : (600 + (kt - 10) * 32 + r3);
      float v[8];
      if (kt >= 10 || k < NE) {
        const float* wr = W + (size_t)k * NCOL + s3 * NH + d0c + hf * 8;
        const f4v a0 = *(const f4v*)wr;
        const f4v a1 = *(const f4v*)(wr + 4);
        v[0] = a0[0]; v[1] = a0[1]; v[2] = a0[2]; v[3] = a0[3];
        v[4] = a1[0]; v[5] = a1[1]; v[6] = a1[2]; v[7] = a1[3];
      } else {
        #pragma unroll
        for (int j = 0; j < 8; ++j) v[j] = 0.f;
      }
      #pragma unroll
      for (int j = 0; j < 8; ++j)
        wT[(s3 * 16 + hf * 8 + j) * 32 + r3] = f2h(v[j]);
      __syncthreads();
      #pragma unroll
      for (int nt = 0; nt < 2; ++nt) {
        const int cL = (gp + nt) * 16 + (ln & 15);
        bfr[nt][kt] = *(const h8v*)((char*)wT + cL * 64 + kgrp * 16);
      }
      __syncthreads();
    }
  }

  // ---- finish detection: fast iff all 32 group members share one XCD ----
  gwait(fl, 1, false);
  bool fast;
  {
    int v = myxcc;
    if (ln < 32) {
      asm volatile("global_load_dword %0, %1, off sc1\n\ts_waitcnt vmcnt(0)"
                   : "=v"(v) : "v"(p.xids + g * 32 + ln) : "memory");
    }
    fast = (__ballot(v != myxcc) == 0ull);
  }

  // ---------------- x-gather (emb[tok] -> f16 LDS, pad 300->320) ----------------
  auto gather_x = [&](int t) {
    const int xrow = tid >> 3;
    const int tok = gids[(size_t)(b0 + xrow) * NS + t];
    const float* ep_ = p.emb + (size_t)tok * NE;
    #pragma unroll
    for (int j = 0; j < 5; ++j) {
      const int c16 = (tid & 7) + j * 8;
      unsigned short tmp[8];
      if (c16 < 37) {
        const f4v v0 = *(const f4v*)(ep_ + c16 * 8);
        const f4v v1 = *(const f4v*)(ep_ + c16 * 8 + 4);
        tmp[0] = f2h(v0[0]); tmp[1] = f2h(v0[1]); tmp[2] = f2h(v0[2]); tmp[3] = f2h(v0[3]);
        tmp[4] = f2h(v1[0]); tmp[5] = f2h(v1[1]); tmp[6] = f2h(v1[2]); tmp[7] = f2h(v1[3]);
      } else if (c16 == 37) {
        const f4v v0 = *(const f4v*)(ep_ + 296);
        tmp[0] = f2h(v0[0]); tmp[1] = f2h(v0[1]); tmp[2] = f2h(v0[2]); tmp[3] = f2h(v0[3]);
        tmp[4] = 0; tmp[5] = 0; tmp[6] = 0; tmp[7] = 0;
      } else {
        #pragma unroll
        for (int q = 0; q < 8; ++q) tmp[q] = 0;
      }
      *(i4v*)(lds + 32768 + xrow * 640 + ((c16 * 16) ^ ((xrow & 7) << 4))) = *(const i4v*)tmp;
    }
  };

  const int arow = mt * 16 + (ln & 15);
  f4v acc0, acc1;
  auto xmfma = [&]() {   // z += x @ W[0:320]
    #pragma unroll
    for (int kt = 0; kt < 10; ++kt) {
      h8v a = *(const h8v*)(lds + 32768 + arow * 640 + (((kt * 4 + kgrp) * 16) ^ ((arow & 7) << 4)));
      acc0 = __builtin_amdgcn_mfma_f32_16x16x32_f16(a, bfr[0][kt], acc0, 0, 0, 0);
      acc1 = __builtin_amdgcn_mfma_f32_16x16x32_f16(a, bfr[1][kt], acc1, 0, 0, 0);
    }
  };

  gather_x(0);
  __syncthreads();
  acc0 = f4v{0.f, 0.f, 0.f, 0.f}; acc1 = f4v{0.f, 0.f, 0.f, 0.f};
  xmfma();

  // ---------------- main recurrence: 128 steps ----------------
  float cR1 = 0.f, cR2 = 0.f, hR1 = 0.f, hR2 = 0.f;
  for (int t = 0; t < NS; ++t) {
    if (t) {
      gwait(fl, t + 1, fast);   // h_t ready (flag t+1)
      // per-lane direct load of this lane's 16 A-fragments of h_t
      const unsigned short* hrow =
          p.hbuf + (size_t)(((t & 1) * 2 + side) * NB + b0 + arow) * NH + kgrp * 8;
      i4v hr[16];
      ld16h((const char*)hrow, hr, fast);
      #pragma unroll
      for (int q = 0; q < 16; ++q) {
        h8v a = __builtin_bit_cast(h8v, hr[q]);
        acc0 = __builtin_amdgcn_mfma_f32_16x16x32_f16(a, bfr[0][10 + q], acc0, 0, 0, 0);
        acc1 = __builtin_amdgcn_mfma_f32_16x16x32_f16(a, bfr[1][10 + q], acc1, 0, 0, 0);
      }
    }
    // D frag: col = lane&15, row = (lane>>4)*4 + rg  (+16*mt)
    #pragma unroll
    for (int rg = 0; rg < 4; ++rg) {
      const int rr = mt * 16 + kgrp * 4 + rg;
      zS[rr * 64 + gp * 16 + (ln & 15)]       = acc0[rg];
      zS[rr * 64 + (gp + 1) * 16 + (ln & 15)] = acc1[rg];
    }
    __syncthreads();

    // cell update (fp32); h_{t+1} stores (mode-dependent)
    {
      unsigned short* dst = p.hbuf + (size_t)(((t + 1) & 1) * 2 + side) * NB * NH;
      const float* z1 = zS + r1 * 64 + dloc;
      const float* z2 = zS + r2 * 64 + dloc;
      float zi = z1[0] + zb1[0], zj = z1[16] + zb1[1], zf = z1[32] + zb1[2], zo = z1[48] + zb1[3];
      float ig = sigm(zi), jg = tanh_(zj), fg = sigm(zf + 1.f), og = sigm(zo);
      float cn = fg * cR1 + ig * jg;
      float hn = og * tanh_(cn);
      if (t < lenL[r1]) { cR1 = cn; hR1 = hn; }
      st16h(&dst[(size_t)(b0 + r1) * NH + d0c + dloc], f2h(hR1), fast);
      zi = z2[0] + zb2[0]; zj = z2[16] + zb2[1]; zf = z2[32] + zb2[2]; zo = z2[48] + zb2[3];
      ig = sigm(zi); jg = tanh_(zj); fg = sigm(zf + 1.f); og = sigm(zo);
      cn = fg * cR2 + ig * jg; hn = og * tanh_(cn);
      if (t < lenL[r2]) { cR2 = cn; hR2 = hn; }
      st16h(&dst[(size_t)(b0 + r2) * NH + d0c + dloc], f2h(hR2), fast);
    }

    grel(fl, ht, t + 2, fast);   // publish h_{t+1}
    if (t < NS - 1) {            // shadow work: x(t+1) gather + x-MFMAs
      gather_x(t + 1);
      __syncthreads();
      acc0 = f4v{0.f, 0.f, 0.f, 0.f}; acc1 = f4v{0.f, 0.f, 0.f, 0.f};
      xmfma();
    }
  }

  // ---------------- epilogue: final h (sc1 always) + dense head ----------------
  st32f_uc(&p.hfin[((size_t)side * NB + b0 + r1) * NH + d0c + dloc], hR1);
  st32f_uc(&p.hfin[((size_t)side * NB + b0 + r2) * NH + d0c + dloc], hR2);
  grel(fl, ht, NS + 2, false);   // flag 130 via IF: hfin ready (cross-XCD consumers)

  if (wid < NB) {
    const int b = wid, btq = b >> 5;
    if (tid < 64) {
      const int gsel = tid >> 5;
      const int* f = p.bar + (gsel * 4 + btq) * 32 + (tid & 31);
      int v = ldflag(f, false);
      while (__ballot(v < NS + 2) != 0ull) {
        __builtin_amdgcn_s_sleep(1);
        v = ldflag(f, false);
      }
    }
    __syncthreads();

    float a0 = 0.f, a1 = 0.f, a2 = 0.f;
    #pragma unroll
    for (int q = 0; q < 4; ++q) {
      const int kk = q * 256 + tid;
      const float* hp = (kk < NH) ? &p.hfin[(size_t)b * NH + kk]
                                  : &p.hfin[((size_t)NB + b) * NH + (kk - NH)];
      const float hv = __hip_atomic_load(hp, __ATOMIC_RELAXED, __HIP_MEMORY_SCOPE_AGENT);
      a0 += hv * p.Wd[kk * 3 + 0];
      a1 += hv * p.Wd[kk * 3 + 1];
      a2 += hv * p.Wd[kk * 3 + 2];
    }
    #pragma unroll
    for (int s = 32; s > 0; s >>= 1) {
      a0 += __shfl_down(a0, s, 64);
      a1 += __shfl_down(a1, s, 64);
      a2 += __shfl_down(a2, s, 64);
    }
    if (ln == 0) { redL[wv_ * 4 + 0] = a0; redL[wv_ * 4 + 1] = a1; redL[wv_ * 4 + 2] = a2; }
    __syncthreads();
    if (tid == 0) {
      p.out[b * 3 + 0] = redL[0] + redL[4] + redL[8]  + redL[12] + p.bd[0];
      p.out[b * 3 + 1] = redL[1] + redL[5] + redL[9]  + redL[13] + p.bd[1];
      p.out[b * 3 + 2] = redL[2] + redL[6] + redL[10] + redL[14] + p.bd[2];
    }
  }
}

extern "C" void kernel_launch(void* const* d_in, const int* in_sizes, int n_in,
                              void* d_out, int out_size, void* d_ws, size_t ws_size,
                              hipStream_t stream) {
  (void)in_sizes; (void)n_in; (void)out_size; (void)ws_size;
  char* ws = (char*)d_ws;
  Params p;
  p.tids = (const int*)d_in[0];
  p.tlen = (const int*)d_in[1];
  p.lids = (const int*)d_in[2];
  p.llen = (const int*)d_in[3];
  p.rids = (const int*)d_in[4];
  p.rlen = (const int*)d_in[5];
  p.emb  = (const float*)d_in[6];
  p.Wl   = (const float*)d_in[7];
  p.bl   = (const float*)d_in[8];
  p.Wr   = (const float*)d_in[9];
  p.br   = (const float*)d_in[10];
  p.Wd   = (const float*)d_in[11];
  p.bd   = (const float*)d_in[12];
  p.out  = (float*)d_out;
  p.bar  = (int*)ws;                                   // 1024 B
  p.xids = (int*)(ws + 1024);                          // 1024 B
  p.hbuf = (unsigned short*)(ws + 2048);               // 2*2*128*512*2 = 524,288 B
  p.hfin = (float*)(ws + 2048 + 524288);               // 2*128*512*4   = 524,288 B
  hipMemsetAsync(ws, 0, 2048, stream);                 // reset flags + xids
  lstm_all<<<dim3(NBLK), dim3(256), 0, stream>>>(p);
}

// Round 6
// 679.819 us; speedup vs baseline: 1.2711x; 1.2711x over previous
//
#include <hip/hip_runtime.h>

#define NB 128   // batch
#define NS 128   // context seq len
#define NT 12    // target seq len
#define NE 300   // embed dim
#define NH 512   // hidden
#define NCOL 2048  // 4*NH
#define WGSC __HIP_MEMORY_SCOPE_WORKGROUP

typedef _Float16 h8v __attribute__((ext_vector_type(8)));
typedef __attribute__((ext_vector_type(4))) float f4v;
typedef __attribute__((ext_vector_type(4))) int   i4v;

__device__ __forceinline__ unsigned short f2h(float f) {
  union { _Float16 h; unsigned short u; } c; c.h = (_Float16)f; return c.u;
}
__device__ __forceinline__ float sigm(float x) { return 1.f / (1.f + __expf(-x)); }
__device__ __forceinline__ float tanh_(float x) { const float e = __expf(2.f * x); return 1.f - 2.f / (e + 1.f); }

// ---- device-scope UNCACHED (sc1, coherence at IF) exchange primitives ----
__device__ __forceinline__ void st16_uc(unsigned short* p, unsigned short v) {
  unsigned vv = v;
  asm volatile("global_store_short %0, %1, off sc1" :: "v"(p), "v"(vv) : "memory");
}
__device__ __forceinline__ void st32f_uc(float* p, float v) {
  asm volatile("global_store_dword %0, %1, off sc1" :: "v"(p), "v"(v) : "memory");
}
__device__ __forceinline__ void st32i_uc(int* p, int v) {
  asm volatile("global_store_dword %0, %1, off sc1" :: "v"(p), "v"(v) : "memory");
}
__device__ __forceinline__ int ldflag(const int* p) {
  int v;
  asm volatile("global_load_dword %0, %1, off sc1\n\ts_waitcnt vmcnt(0)" : "=v"(v) : "v"(p) : "memory");
  return v;
}
// 16 x 16B sc1 loads of one hbuf row (64B stride), one vmcnt at end
__device__ __forceinline__ void ld16h(const char* a, i4v* r) {
  asm volatile(
    "global_load_dwordx4 %0, %16, off sc1\n\t"
    "global_load_dwordx4 %1, %16, off offset:64 sc1\n\t"
    "global_load_dwordx4 %2, %16, off offset:128 sc1\n\t"
    "global_load_dwordx4 %3, %16, off offset:192 sc1\n\t"
    "global_load_dwordx4 %4, %16, off offset:256 sc1\n\t"
    "global_load_dwordx4 %5, %16, off offset:320 sc1\n\t"
    "global_load_dwordx4 %6, %16, off offset:384 sc1\n\t"
    "global_load_dwordx4 %7, %16, off offset:448 sc1\n\t"
    "global_load_dwordx4 %8, %16, off offset:512 sc1\n\t"
    "global_load_dwordx4 %9, %16, off offset:576 sc1\n\t"
    "global_load_dwordx4 %10, %16, off offset:640 sc1\n\t"
    "global_load_dwordx4 %11, %16, off offset:704 sc1\n\t"
    "global_load_dwordx4 %12, %16, off offset:768 sc1\n\t"
    "global_load_dwordx4 %13, %16, off offset:832 sc1\n\t"
    "global_load_dwordx4 %14, %16, off offset:896 sc1\n\t"
    "global_load_dwordx4 %15, %16, off offset:960 sc1\n\t"
    "s_waitcnt vmcnt(0)"
    : "=&v"(r[0]), "=&v"(r[1]), "=&v"(r[2]), "=&v"(r[3]),
      "=&v"(r[4]), "=&v"(r[5]), "=&v"(r[6]), "=&v"(r[7]),
      "=&v"(r[8]), "=&v"(r[9]), "=&v"(r[10]), "=&v"(r[11]),
      "=&v"(r[12]), "=&v"(r[13]), "=&v"(r[14]), "=&v"(r[15])
    : "v"(a) : "memory");
}

struct Params {
  const int *tids, *tlen, *lids, *llen, *rids, *rlen;
  const float *emb, *Wl, *bl, *Wr, *br, *Wd, *bd;
  float* out;
  unsigned short* hbuf;  // [2(pp)][2(side)][NB][NH] f16 (sc1 access)
  float* hfin;           // [2(side)][NB][NH] fp32 (sc1 access)
  int* bar;              // flags [8 groups][32 slots]
};

// LDS monotonic-counter helpers (workgroup scope)
__device__ __forceinline__ void lspin(int* c, int tgt) {
  while (__hip_atomic_load(c, __ATOMIC_RELAXED, WGSC) < tgt) {}
  __builtin_amdgcn_fence(__ATOMIC_ACQUIRE, "workgroup");
}
__device__ __forceinline__ void larrive(int* c) {
  __hip_atomic_fetch_add(c, 1, __ATOMIC_ACQ_REL, WGSC);
}

// LDS layout
#define OFF_XS   0        // 32 x 640B f16, XOR-swizzled (x staging)       20480
#define OFF_ZX   20480    // 2 x [32][64] f32 zx ring                      16384
#define OFF_WTH  36864    // 4KB transpose scratch (h role)
#define OFF_WTX  40960    // 4KB transpose scratch (x role)
#define OFF_ZS   45056    // [32][64] f32 gate exchange                     8192
#define LDS_SZ   53248
// prologue: meanTT f32[300*32] aliases lds+0..38400 (dead before phase 3)

__global__ __launch_bounds__(512, 2) void lstm_all(Params p) {
  __shared__ __align__(16) char lds[LDS_SZ];
  __shared__ int lenL[32];
  __shared__ float redL[8][4];
  __shared__ int cnt[4];   // 0:hbar 1:xbar 2:prod 3:cons

  const int tid = threadIdx.x;
  const int wid = blockIdx.x;
  if (tid < 4) cnt[tid] = 0;

  const int bt = wid & 3, side = (wid >> 2) & 1, ht = wid >> 3;
  const int b0 = bt * 32, d0c = ht * 16;
  const int* lenp = side ? p.rlen : p.llen;
  const int* gids = side ? p.rids : p.lids;
  const float* W = side ? p.Wr : p.Wl;
  const float* bias = side ? p.br : p.bl;
  int* fl = p.bar + (side * 4 + bt) * 32;

  const bool isH = tid < 256;          // waves 0-3: h recurrence; 4-7: x pipeline
  const int wv = tid >> 6;             // 0..7
  const int ln = tid & 63;
  const int lwv = isH ? wv : (wv - 4); // role-local wave 0..3
  const int mt = lwv & 1;              // 16-row half
  const int gp = (lwv >> 1) * 2;       // gate pair
  const int kgrp = ln >> 4;
  const int arow = mt * 16 + (ln & 15);
  const int stid = tid & 255;

  float* meanTT = (float*)lds;
  float* zS = (float*)(lds + OFF_ZS);

  // ---------------- phase 1: mean_t (all 512 threads, transposed [k][r]) ----------------
  {
    const int r = tid >> 4, l16 = tid & 15;
    const int b = b0 + r;
    const int Lt = p.tlen[b];
    const float inv = 1.f / (float)Lt;
    int toks[NT];
    #pragma unroll
    for (int t = 0; t < NT; ++t) toks[t] = p.tids[b * NT + t];
    for (int k = l16; k < NE; k += 16) {
      float s = 0.f;
      #pragma unroll
      for (int t = 0; t < NT; ++t)
        if (t < Lt) s += p.emb[(size_t)toks[t] * NE + k];
      meanTT[k * 32 + r] = s * inv;
    }
    if (tid < 32) lenL[tid] = lenp[b0 + tid];
  }
  __syncthreads();

  // ---------------- phase 2: z_base (h-threads only) ----------------
  const int dloc = stid & 15;
  const int r1 = stid >> 4;
  const int r2 = r1 + 16;
  float zb1[4], zb2[4];
  if (isH) {
    const int c = tid & 63, rq = tid >> 6;
    const int gcol = (c >> 4) * NH + d0c + (c & 15);
    float acc[8];
    #pragma unroll
    for (int i = 0; i < 8; ++i) acc[i] = 0.f;
    const float* wp = W + (size_t)NE * NCOL + gcol;
    for (int k = 0; k < NE; ++k) {
      const float wvv = wp[(size_t)k * NCOL];
      const f4v m0 = *(const f4v*)(meanTT + k * 32 + rq * 8);
      const f4v m1 = *(const f4v*)(meanTT + k * 32 + rq * 8 + 4);
      acc[0] += m0[0] * wvv; acc[1] += m0[1] * wvv; acc[2] += m0[2] * wvv; acc[3] += m0[3] * wvv;
      acc[4] += m1[0] * wvv; acc[5] += m1[1] * wvv; acc[6] += m1[2] * wvv; acc[7] += m1[3] * wvv;
    }
    #pragma unroll
    for (int rr = 0; rr < 8; ++rr) zS[(rq * 8 + rr) * 64 + c] = acc[rr];
  }
  __syncthreads();
  if (isH) {
    #pragma unroll
    for (int g = 0; g < 4; ++g) {
      zb1[g] = zS[r1 * 64 + g * 16 + dloc] + bias[g * NH + d0c + dloc];
      zb2[g] = zS[r2 * 64 + g * 16 + dloc] + bias[g * NH + d0c + dloc];
    }
  }
  __syncthreads();   // meanTT + zS dead; wT regions free

  // ---------------- phase 3: W -> register B-fragments (f16) ----------------
  // h-role: bfr[2][0..15] = Wh rows 600..1112 ; x-role: bfr[2][0..9] = Wx rows 0..320
  h8v bfr[2][16];
  {
    unsigned short* wT = (unsigned short*)(lds + (isH ? OFF_WTH : OFF_WTX));
    const int r3 = stid >> 3, part = stid & 7, s3 = part >> 1, hf = part & 1;
    for (int i = 0; i < 16; ++i) {
      const bool act = isH || (i < 10);
      if (act) {
        const int k = isH ? (600 + i * 32 + r3) : (i * 32 + r3);
        float v[8];
        if (isH || k < NE) {
          const float* wr = W + (size_t)k * NCOL + s3 * NH + d0c + hf * 8;
          const f4v a0 = *(const f4v*)wr;
          const f4v a1 = *(const f4v*)(wr + 4);
          v[0] = a0[0]; v[1] = a0[1]; v[2] = a0[2]; v[3] = a0[3];
          v[4] = a1[0]; v[5] = a1[1]; v[6] = a1[2]; v[7] = a1[3];
        } else {
          #pragma unroll
          for (int j = 0; j < 8; ++j) v[j] = 0.f;
        }
        #pragma unroll
        for (int j = 0; j < 8; ++j)
          wT[(s3 * 16 + hf * 8 + j) * 32 + r3] = f2h(v[j]);
      }
      __syncthreads();
      if (act) {
        #pragma unroll
        for (int nt = 0; nt < 2; ++nt) {
          const int cL = (gp + nt) * 16 + (ln & 15);
          bfr[nt][i] = *(const h8v*)((char*)wT + cL * 64 + kgrp * 16);
        }
      }
      __syncthreads();
    }
  }

  // ================= role split =================
  if (isH) {
    // ---------------- h-recurrence waves ----------------
    int he = 0;
    auto hbar = [&]() {
      ++he;
      if (ln == 0) larrive(&cnt[0]);
      while (__hip_atomic_load(&cnt[0], __ATOMIC_RELAXED, WGSC) < 4 * he) {}
      __builtin_amdgcn_fence(__ATOMIC_ACQUIRE, "workgroup");
    };
    float cR1 = 0.f, cR2 = 0.f, hR1 = 0.f, hR2 = 0.f;
    for (int t = 0; t < NS; ++t) {
      // 1. zx(t) from x-waves (they run ~2 ahead; usually no wait)
      lspin(&cnt[2], 4 * (t + 1));
      const float* zx = (const float*)(lds + OFF_ZX + (t & 1) * 8192);
      f4v acc0, acc1;
      #pragma unroll
      for (int rg = 0; rg < 4; ++rg) {
        const int rr = mt * 16 + kgrp * 4 + rg;
        acc0[rg] = zx[rr * 64 + gp * 16 + (ln & 15)];
        acc1[rg] = zx[rr * 64 + (gp + 1) * 16 + (ln & 15)];
      }
      if (ln == 0) larrive(&cnt[3]);   // consumption(t) done (reads retired by acq_rel)

      // 2. peers' h_t
      if (t) {
        if (lwv == 0) {
          const int* f = fl + (ln & 31);
          int v = ldflag(f);
          while (__ballot(v < t) != 0ull) { __builtin_amdgcn_s_sleep(1); v = ldflag(f); }
        }
      }
      hbar();
      if (t) {
        const char* hrow = (const char*)(p.hbuf
            + (size_t)(((t & 1) * 2 + side) * NB + b0 + arow) * NH + kgrp * 8);
        i4v hr[16];
        ld16h(hrow, hr);
        #pragma unroll
        for (int q = 0; q < 16; ++q) {
          h8v a = __builtin_bit_cast(h8v, hr[q]);
          acc0 = __builtin_amdgcn_mfma_f32_16x16x32_f16(a, bfr[0][q], acc0, 0, 0, 0);
          acc1 = __builtin_amdgcn_mfma_f32_16x16x32_f16(a, bfr[1][q], acc1, 0, 0, 0);
        }
      }

      // 3. gate exchange
      #pragma unroll
      for (int rg = 0; rg < 4; ++rg) {
        const int rr = mt * 16 + kgrp * 4 + rg;
        zS[rr * 64 + gp * 16 + (ln & 15)]       = acc0[rg];
        zS[rr * 64 + (gp + 1) * 16 + (ln & 15)] = acc1[rg];
      }
      hbar();

      // 4. cell update + h_{t+1} stores (sc1)
      {
        unsigned short* dst = p.hbuf + (size_t)(((t + 1) & 1) * 2 + side) * NB * NH;
        const float* z1 = zS + r1 * 64 + dloc;
        const float* z2 = zS + r2 * 64 + dloc;
        float zi = z1[0] + zb1[0], zj = z1[16] + zb1[1], zf = z1[32] + zb1[2], zo = z1[48] + zb1[3];
        float ig = sigm(zi), jg = tanh_(zj), fg = sigm(zf + 1.f), og = sigm(zo);
        float cn = fg * cR1 + ig * jg;
        float hn = og * tanh_(cn);
        if (t < lenL[r1]) { cR1 = cn; hR1 = hn; }
        st16_uc(&dst[(size_t)(b0 + r1) * NH + d0c + dloc], f2h(hR1));
        zi = z2[0] + zb2[0]; zj = z2[16] + zb2[1]; zf = z2[32] + zb2[2]; zo = z2[48] + zb2[3];
        ig = sigm(zi); jg = tanh_(zj); fg = sigm(zf + 1.f); og = sigm(zo);
        cn = fg * cR2 + ig * jg; hn = og * tanh_(cn);
        if (t < lenL[r2]) { cR2 = cn; hR2 = hn; }
        st16_uc(&dst[(size_t)(b0 + r2) * NH + d0c + dloc], f2h(hR2));
      }

      // 5. release
      asm volatile("s_waitcnt vmcnt(0)" ::: "memory");
      hbar();
      if (tid == 0) st32i_uc(fl + ht, t + 1);
    }

    // epilogue: final h -> hfin (sc1), flag 129
    st32f_uc(&p.hfin[((size_t)side * NB + b0 + r1) * NH + d0c + dloc], hR1);
    st32f_uc(&p.hfin[((size_t)side * NB + b0 + r2) * NH + d0c + dloc], hR2);
    asm volatile("s_waitcnt vmcnt(0)" ::: "memory");
    hbar();
    if (tid == 0) st32i_uc(fl + ht, NS + 1);
  } else {
    // ---------------- x-pipeline waves: produce zx(n) = x_n @ Wx, 2 ahead ----------------
    int xe = 0;
    auto xbar = [&]() {
      ++xe;
      if (ln == 0) larrive(&cnt[1]);
      while (__hip_atomic_load(&cnt[1], __ATOMIC_RELAXED, WGSC) < 4 * xe) {}
      __builtin_amdgcn_fence(__ATOMIC_ACQUIRE, "workgroup");
    };
    for (int n = 0; n < NS; ++n) {
      if (n >= 2) lspin(&cnt[3], 4 * (n - 1));  // ring slot free
      // gather x_n: emb[tok] -> f16 xS (pad 300->320), 256 threads
      {
        const int xrow = stid >> 3;
        const int tok = gids[(size_t)(b0 + xrow) * NS + n];
        const float* ep_ = p.emb + (size_t)tok * NE;
        #pragma unroll
        for (int j = 0; j < 5; ++j) {
          const int c16 = (stid & 7) + j * 8;
          unsigned short tmp[8];
          if (c16 < 37) {
            const f4v v0 = *(const f4v*)(ep_ + c16 * 8);
            const f4v v1 = *(const f4v*)(ep_ + c16 * 8 + 4);
            tmp[0] = f2h(v0[0]); tmp[1] = f2h(v0[1]); tmp[2] = f2h(v0[2]); tmp[3] = f2h(v0[3]);
            tmp[4] = f2h(v1[0]); tmp[5] = f2h(v1[1]); tmp[6] = f2h(v1[2]); tmp[7] = f2h(v1[3]);
          } else if (c16 == 37) {
            const f4v v0 = *(const f4v*)(ep_ + 296);
            tmp[0] = f2h(v0[0]); tmp[1] = f2h(v0[1]); tmp[2] = f2h(v0[2]); tmp[3] = f2h(v0[3]);
            tmp[4] = 0; tmp[5] = 0; tmp[6] = 0; tmp[7] = 0;
          } else {
            #pragma unroll
            for (int q = 0; q < 8; ++q) tmp[q] = 0;
          }
          *(i4v*)(lds + OFF_XS + xrow * 640 + ((c16 * 16) ^ ((xrow & 7) << 4))) = *(const i4v*)tmp;
        }
      }
      xbar();
      // zx = x @ Wx (10 kt x 2 N-tiles)
      f4v a0 = {0.f, 0.f, 0.f, 0.f}, a1 = {0.f, 0.f, 0.f, 0.f};
      #pragma unroll
      for (int kt = 0; kt < 10; ++kt) {
        h8v a = *(const h8v*)(lds + OFF_XS + arow * 640 + (((kt * 4 + kgrp) * 16) ^ ((arow & 7) << 4)));
        a0 = __builtin_amdgcn_mfma_f32_16x16x32_f16(a, bfr[0][kt], a0, 0, 0, 0);
        a1 = __builtin_amdgcn_mfma_f32_16x16x32_f16(a, bfr[1][kt], a1, 0, 0, 0);
      }
      float* zx = (float*)(lds + OFF_ZX + (n & 1) * 8192);
      #pragma unroll
      for (int rg = 0; rg < 4; ++rg) {
        const int rr = mt * 16 + kgrp * 4 + rg;
        zx[rr * 64 + gp * 16 + (ln & 15)]       = a0[rg];
        zx[rr * 64 + (gp + 1) * 16 + (ln & 15)] = a1[rg];
      }
      if (ln == 0) larrive(&cnt[2]);   // production(n) published (release)
      xbar();                          // xS reads done before next gather
    }
  }

  // ---------------- dense head (blocks 0..127, all 512 threads) ----------------
  if (wid < NB) {
    const int b = wid, btq = b >> 5;
    if (tid < 64) {
      const int gsel = tid >> 5;
      const int* f = p.bar + (gsel * 4 + btq) * 32 + (tid & 31);
      int v = ldflag(f);
      while (__ballot(v < NS + 1) != 0ull) { __builtin_amdgcn_s_sleep(1); v = ldflag(f); }
    }
    __syncthreads();

    float a0 = 0.f, a1 = 0.f, a2 = 0.f;
    #pragma unroll
    for (int q = 0; q < 2; ++q) {
      const int kk = q * 512 + tid;
      const int hs = kk >> 9, dim = kk & 511;
      const float* hp = &p.hfin[((size_t)hs * NB + b) * NH + dim];
      const float hv = __hip_atomic_load(hp, __ATOMIC_RELAXED, __HIP_MEMORY_SCOPE_AGENT);
      a0 += hv * p.Wd[kk * 3 + 0];
      a1 += hv * p.Wd[kk * 3 + 1];
      a2 += hv * p.Wd[kk * 3 + 2];
    }
    #pragma unroll
    for (int s = 32; s > 0; s >>= 1) {
      a0 += __shfl_down(a0, s, 64);
      a1 += __shfl_down(a1, s, 64);
      a2 += __shfl_down(a2, s, 64);
    }
    if (ln == 0) { redL[wv][0] = a0; redL[wv][1] = a1; redL[wv][2] = a2; }
    __syncthreads();
    if (tid == 0) {
      float o0 = p.bd[0], o1 = p.bd[1], o2 = p.bd[2];
      #pragma unroll
      for (int w = 0; w < 8; ++w) { o0 += redL[w][0]; o1 += redL[w][1]; o2 += redL[w][2]; }
      p.out[b * 3 + 0] = o0;
      p.out[b * 3 + 1] = o1;
      p.out[b * 3 + 2] = o2;
    }
  }
}

extern "C" void kernel_launch(void* const* d_in, const int* in_sizes, int n_in,
                              void* d_out, int out_size, void* d_ws, size_t ws_size,
                              hipStream_t stream) {
  (void)in_sizes; (void)n_in; (void)out_size; (void)ws_size;
  char* ws = (char*)d_ws;
  Params p;
  p.tids = (const int*)d_in[0];
  p.tlen = (const int*)d_in[1];
  p.lids = (const int*)d_in[2];
  p.llen = (const int*)d_in[3];
  p.rids = (const int*)d_in[4];
  p.rlen = (const int*)d_in[5];
  p.emb  = (const float*)d_in[6];
  p.Wl   = (const float*)d_in[7];
  p.bl   = (const float*)d_in[8];
  p.Wr   = (const float*)d_in[9];
  p.br   = (const float*)d_in[10];
  p.Wd   = (const float*)d_in[11];
  p.bd   = (const float*)d_in[12];
  p.out  = (float*)d_out;
  p.bar  = (int*)ws;                                   // 1024 B
  p.hbuf = (unsigned short*)(ws + 1024);               // 2*2*128*512*2 = 524,288 B
  p.hfin = (float*)(ws + 1024 + 524288);               // 2*128*512*4   = 524,288 B
  hipMemsetAsync(ws, 0, 1024, stream);                 // reset flags each launch
  lstm_all<<<dim3(256), dim3(512), 0, stream>>>(p);
}

// Round 7
// 674.446 us; speedup vs baseline: 1.2812x; 1.0080x over previous
//
#include <hip/hip_runtime.h>

#define NB 128   // batch
#define NS 128   // context seq len
#define NT 12    // target seq len
#define NE 300   // embed dim
#define NH 512   // hidden
#define NCOL 2048  // 4*NH
#define WGSC __HIP_MEMORY_SCOPE_WORKGROUP

typedef _Float16 h8v __attribute__((ext_vector_type(8)));
typedef __attribute__((ext_vector_type(4))) float f4v;
typedef __attribute__((ext_vector_type(4))) int   i4v;

__device__ __forceinline__ unsigned short f2h(float f) {
  union { _Float16 h; unsigned short u; } c; c.h = (_Float16)f; return c.u;
}
__device__ __forceinline__ float sigm(float x) { return 1.f / (1.f + __expf(-x)); }
__device__ __forceinline__ float tanh_(float x) { const float e = __expf(2.f * x); return 1.f - 2.f / (e + 1.f); }

// ---- device-scope UNCACHED (sc1, coherence at IF) exchange primitives ----
__device__ __forceinline__ void st32f_uc(float* p, float v) {
  asm volatile("global_store_dword %0, %1, off sc1" :: "v"(p), "v"(v) : "memory");
}
__device__ __forceinline__ void st32i_uc(int* p, int v) {
  asm volatile("global_store_dword %0, %1, off sc1" :: "v"(p), "v"(v) : "memory");
}
__device__ __forceinline__ int ldflag(const int* p) {
  int v;
  asm volatile("global_load_dword %0, %1, off sc1\n\ts_waitcnt vmcnt(0)" : "=v"(v) : "v"(p) : "memory");
  return v;
}
// 16 x 16B sc1 loads of one hbuf row (64B stride); waits only first 8 (vmcnt(8))
__device__ __forceinline__ void ld16h_a(const char* a, i4v* r) {
  asm volatile(
    "global_load_dwordx4 %0, %16, off sc1\n\t"
    "global_load_dwordx4 %1, %16, off offset:64 sc1\n\t"
    "global_load_dwordx4 %2, %16, off offset:128 sc1\n\t"
    "global_load_dwordx4 %3, %16, off offset:192 sc1\n\t"
    "global_load_dwordx4 %4, %16, off offset:256 sc1\n\t"
    "global_load_dwordx4 %5, %16, off offset:320 sc1\n\t"
    "global_load_dwordx4 %6, %16, off offset:384 sc1\n\t"
    "global_load_dwordx4 %7, %16, off offset:448 sc1\n\t"
    "global_load_dwordx4 %8, %16, off offset:512 sc1\n\t"
    "global_load_dwordx4 %9, %16, off offset:576 sc1\n\t"
    "global_load_dwordx4 %10, %16, off offset:640 sc1\n\t"
    "global_load_dwordx4 %11, %16, off offset:704 sc1\n\t"
    "global_load_dwordx4 %12, %16, off offset:768 sc1\n\t"
    "global_load_dwordx4 %13, %16, off offset:832 sc1\n\t"
    "global_load_dwordx4 %14, %16, off offset:896 sc1\n\t"
    "global_load_dwordx4 %15, %16, off offset:960 sc1\n\t"
    "s_waitcnt vmcnt(8)"
    : "=&v"(r[0]), "=&v"(r[1]), "=&v"(r[2]), "=&v"(r[3]),
      "=&v"(r[4]), "=&v"(r[5]), "=&v"(r[6]), "=&v"(r[7]),
      "=&v"(r[8]), "=&v"(r[9]), "=&v"(r[10]), "=&v"(r[11]),
      "=&v"(r[12]), "=&v"(r[13]), "=&v"(r[14]), "=&v"(r[15])
    : "v"(a) : "memory");
}

struct Params {
  const int *tids, *tlen, *lids, *llen, *rids, *rlen;
  const float *emb, *Wl, *bl, *Wr, *br, *Wd, *bd;
  float* out;
  unsigned short* hbuf;  // [2(pp)][2(side)][NB][NH] f16 (sc1 access)
  float* hfin;           // [2(side)][NB][NH] fp32 (sc1 access)
  int* bar;              // flags [8 groups][32 slots]
};

// LDS monotonic-counter helpers (workgroup scope)
__device__ __forceinline__ void lspin(int* c, int tgt) {
  while (__hip_atomic_load(c, __ATOMIC_RELAXED, WGSC) < tgt) {}
  __builtin_amdgcn_fence(__ATOMIC_ACQUIRE, "workgroup");
}
__device__ __forceinline__ void larrive(int* c) {
  __hip_atomic_fetch_add(c, 1, __ATOMIC_ACQ_REL, WGSC);
}

// LDS layout (main loop):
//   XS   @ 0      : 32 x 640B f16, XOR-swizzled (x staging)      20480
//   ZX   @ 20480  : 3-slot ring, [32][64] f32 each (8KB/slot)    24576
//   ZS   @ 45056  : [32][64] f32 gate exchange                    8192
//   HOUT @ 53248  : [32][16] f16 h-publication staging            1024
// prologue aliases (dead before main loop):
//   meanTT f32[300*32] @ 0..38400 ; WTH @ 45056 (zS area, h-internal order);
//   WTX @ 40960 (ZX slot2 tail, x-internal order)
#define OFF_XS   0
#define OFF_ZX   20480
#define OFF_ZS   45056
#define OFF_HOUT 53248
#define OFF_WTH  45056
#define OFF_WTX  40960
#define LDS_SZ   54272

__global__ __launch_bounds__(512, 2) void lstm_all(Params p) {
  __shared__ __align__(16) char lds[LDS_SZ];
  __shared__ int lenL[32];
  __shared__ float redL[8][4];
  __shared__ int cnt[4];   // 0:hbar 1:xbar 2:prod 3:cons

  const int tid = threadIdx.x;
  const int wid = blockIdx.x;
  if (tid < 4) cnt[tid] = 0;

  const int bt = wid & 3, side = (wid >> 2) & 1, ht = wid >> 3;
  const int b0 = bt * 32, d0c = ht * 16;
  const int* lenp = side ? p.rlen : p.llen;
  const int* gids = side ? p.rids : p.lids;
  const float* W = side ? p.Wr : p.Wl;
  const float* bias = side ? p.br : p.bl;
  int* fl = p.bar + (side * 4 + bt) * 32;

  const bool isH = tid < 256;          // waves 0-3: h recurrence; 4-7: x pipeline
  const int wv = tid >> 6;
  const int ln = tid & 63;
  const int lwv = isH ? wv : (wv - 4);
  const int mt = lwv & 1;
  const int gp = (lwv >> 1) * 2;
  const int kgrp = ln >> 4;
  const int arow = mt * 16 + (ln & 15);
  const int stid = tid & 255;

  float* meanTT = (float*)lds;
  float* zS = (float*)(lds + OFF_ZS);

  // ---------------- phase 1: mean_t (all 512 threads, transposed [k][r]) ----------------
  {
    const int r = tid >> 4, l16 = tid & 15;
    const int b = b0 + r;
    const int Lt = p.tlen[b];
    const float inv = 1.f / (float)Lt;
    int toks[NT];
    #pragma unroll
    for (int t = 0; t < NT; ++t) toks[t] = p.tids[b * NT + t];
    for (int k = l16; k < NE; k += 16) {
      float s = 0.f;
      #pragma unroll
      for (int t = 0; t < NT; ++t)
        if (t < Lt) s += p.emb[(size_t)toks[t] * NE + k];
      meanTT[k * 32 + r] = s * inv;
    }
    if (tid < 32) lenL[tid] = lenp[b0 + tid];
  }
  __syncthreads();   // the ONLY block-wide barrier before the dense head

  if (isH) {
    // ================= h role (waves 0-3) =================
    int he = 0;
    auto hbar = [&]() {
      ++he;
      if (ln == 0) larrive(&cnt[0]);
      while (__hip_atomic_load(&cnt[0], __ATOMIC_RELAXED, WGSC) < 4 * he) {}
      __builtin_amdgcn_fence(__ATOMIC_ACQUIRE, "workgroup");
    };
    const int dloc = stid & 15;
    const int r1 = stid >> 4;
    const int r2 = r1 + 16;

    // -------- phase 2: z_base = bias + mean @ W[300:600] --------
    float zb1[4], zb2[4];
    {
      const int c = tid & 63, rq = tid >> 6;
      const int gcol = (c >> 4) * NH + d0c + (c & 15);
      float acc[8];
      #pragma unroll
      for (int i = 0; i < 8; ++i) acc[i] = 0.f;
      const float* wp = W + (size_t)NE * NCOL + gcol;
      for (int k = 0; k < NE; ++k) {
        const float wvv = wp[(size_t)k * NCOL];
        const f4v m0 = *(const f4v*)(meanTT + k * 32 + rq * 8);
        const f4v m1 = *(const f4v*)(meanTT + k * 32 + rq * 8 + 4);
        acc[0] += m0[0] * wvv; acc[1] += m0[1] * wvv; acc[2] += m0[2] * wvv; acc[3] += m0[3] * wvv;
        acc[4] += m1[0] * wvv; acc[5] += m1[1] * wvv; acc[6] += m1[2] * wvv; acc[7] += m1[3] * wvv;
      }
      #pragma unroll
      for (int rr = 0; rr < 8; ++rr) zS[(rq * 8 + rr) * 64 + c] = acc[rr];
    }
    hbar();   // zS ready; meanTT dead -> releases x role (cnt[0] >= 4)
    #pragma unroll
    for (int g = 0; g < 4; ++g) {
      zb1[g] = zS[r1 * 64 + g * 16 + dloc] + bias[g * NH + d0c + dloc];
      zb2[g] = zS[r2 * 64 + g * 16 + dloc] + bias[g * NH + d0c + dloc];
    }
    hbar();   // zb extracted; zS/WTH free

    // -------- phase 3h: Wh -> register B-fragments (16 K-tiles) --------
    h8v hfr[2][16];
    {
      unsigned short* wT = (unsigned short*)(lds + OFF_WTH);
      const int r3 = stid >> 3, part = stid & 7, s3 = part >> 1, hf = part & 1;
      for (int i = 0; i < 16; ++i) {
        const int k = 600 + i * 32 + r3;
        const float* wr = W + (size_t)k * NCOL + s3 * NH + d0c + hf * 8;
        const f4v a0 = *(const f4v*)wr;
        const f4v a1 = *(const f4v*)(wr + 4);
        #pragma unroll
        for (int j = 0; j < 4; ++j) wT[(s3 * 16 + hf * 8 + j) * 32 + r3] = f2h(a0[j]);
        #pragma unroll
        for (int j = 0; j < 4; ++j) wT[(s3 * 16 + hf * 8 + 4 + j) * 32 + r3] = f2h(a1[j]);
        hbar();
        #pragma unroll
        for (int nt = 0; nt < 2; ++nt) {
          const int cL = (gp + nt) * 16 + (ln & 15);
          hfr[nt][i] = *(const h8v*)((char*)wT + cL * 64 + kgrp * 16);
        }
        hbar();
      }
    }

    // -------- main recurrence --------
    float cR1 = 0.f, cR2 = 0.f, hR1 = 0.f, hR2 = 0.f;
    for (int t = 0; t < NS; ++t) {
      // 1. zx(t) from ring (x waves run ahead)
      lspin(&cnt[2], 4 * (t + 1));
      const float* zx = (const float*)(lds + OFF_ZX + (t % 3) * 8192);
      f4v acc0, acc1;
      #pragma unroll
      for (int rg = 0; rg < 4; ++rg) {
        const int rr = mt * 16 + kgrp * 4 + rg;
        acc0[rg] = zx[rr * 64 + gp * 16 + (ln & 15)];
        acc1[rg] = zx[rr * 64 + (gp + 1) * 16 + (ln & 15)];
      }
      if (ln == 0) larrive(&cnt[3]);

      // 2. detect peers' h_t (every wave polls) then load + interleaved MFMA
      if (t) {
        {
          int v = NS + 9;
          const int* f = fl + (ln & 31);
          if (ln < 32) v = ldflag(f);
          while (__ballot(v < t) != 0ull) { if (ln < 32) v = ldflag(f); }
        }
        const char* hrow = (const char*)(p.hbuf
            + (size_t)(((t & 1) * 2 + side) * NB + b0 + arow) * NH + kgrp * 8);
        i4v hr[16];
        ld16h_a(hrow, hr);   // 16 loads issued, first 8 complete
        #pragma unroll
        for (int q = 0; q < 8; ++q) {
          h8v a = __builtin_bit_cast(h8v, hr[q]);
          acc0 = __builtin_amdgcn_mfma_f32_16x16x32_f16(a, hfr[0][q], acc0, 0, 0, 0);
          acc1 = __builtin_amdgcn_mfma_f32_16x16x32_f16(a, hfr[1][q], acc1, 0, 0, 0);
        }
        __builtin_amdgcn_sched_barrier(0);
        asm volatile("s_waitcnt vmcnt(0)" ::: "memory");
        __builtin_amdgcn_sched_barrier(0);
        #pragma unroll
        for (int q = 8; q < 16; ++q) {
          h8v a = __builtin_bit_cast(h8v, hr[q]);
          acc0 = __builtin_amdgcn_mfma_f32_16x16x32_f16(a, hfr[0][q], acc0, 0, 0, 0);
          acc1 = __builtin_amdgcn_mfma_f32_16x16x32_f16(a, hfr[1][q], acc1, 0, 0, 0);
        }
      }

      // 3. gate exchange
      #pragma unroll
      for (int rg = 0; rg < 4; ++rg) {
        const int rr = mt * 16 + kgrp * 4 + rg;
        zS[rr * 64 + gp * 16 + (ln & 15)]       = acc0[rg];
        zS[rr * 64 + (gp + 1) * 16 + (ln & 15)] = acc1[rg];
      }
      hbar();

      // 4. cell update; h_{t+1} -> LDS staging
      {
        unsigned short* hOut = (unsigned short*)(lds + OFF_HOUT);
        const float* z1 = zS + r1 * 64 + dloc;
        const float* z2 = zS + r2 * 64 + dloc;
        float zi = z1[0] + zb1[0], zj = z1[16] + zb1[1], zf = z1[32] + zb1[2], zo = z1[48] + zb1[3];
        float ig = sigm(zi), jg = tanh_(zj), fg = sigm(zf + 1.f), og = sigm(zo);
        float cn = fg * cR1 + ig * jg;
        float hn = og * tanh_(cn);
        if (t < lenL[r1]) { cR1 = cn; hR1 = hn; }
        hOut[r1 * 16 + dloc] = f2h(hR1);
        zi = z2[0] + zb2[0]; zj = z2[16] + zb2[1]; zf = z2[32] + zb2[2]; zo = z2[48] + zb2[3];
        ig = sigm(zi); jg = tanh_(zj); fg = sigm(zf + 1.f); og = sigm(zo);
        cn = fg * cR2 + ig * jg; hn = og * tanh_(cn);
        if (t < lenL[r2]) { cR2 = cn; hR2 = hn; }
        hOut[r2 * 16 + dloc] = f2h(hR2);
      }
      hbar();

      // 5. rotating publisher wave: 64 x 16B sc1 stores + drain + flag
      if (lwv == (t & 3)) {
        const int row = ln >> 1, half = ln & 1;
        i4v hv = *(const i4v*)(lds + OFF_HOUT + row * 32 + half * 16);
        unsigned short* dst = p.hbuf
            + (size_t)((((t + 1) & 1) * 2 + side) * NB + b0 + row) * NH + d0c + half * 8;
        asm volatile("global_store_dwordx4 %0, %1, off sc1\n\ts_waitcnt vmcnt(0)"
                     :: "v"(dst), "v"(hv) : "memory");
        if (ln == 0) st32i_uc(fl + ht, t + 1);
      }
    }

    // -------- epilogue: final h -> hfin (sc1), flag NS+1 --------
    st32f_uc(&p.hfin[((size_t)side * NB + b0 + r1) * NH + d0c + dloc], hR1);
    st32f_uc(&p.hfin[((size_t)side * NB + b0 + r2) * NH + d0c + dloc], hR2);
    asm volatile("s_waitcnt vmcnt(0)" ::: "memory");
    hbar();
    if (tid == 0) st32i_uc(fl + ht, NS + 1);
  } else {
    // ================= x role (waves 4-7) =================
    int xe = 0;
    auto xbar = [&]() {
      ++xe;
      if (ln == 0) larrive(&cnt[1]);
      while (__hip_atomic_load(&cnt[1], __ATOMIC_RELAXED, WGSC) < 4 * xe) {}
      __builtin_amdgcn_fence(__ATOMIC_ACQUIRE, "workgroup");
    };

    // -------- phase 3x: Wx -> register B-fragments (10 K-tiles) --------
    h8v xfr[2][10];
    {
      unsigned short* wT = (unsigned short*)(lds + OFF_WTX);
      const int r3 = stid >> 3, part = stid & 7, s3 = part >> 1, hf = part & 1;
      for (int i = 0; i < 10; ++i) {
        const int k = i * 32 + r3;
        float v[8];
        if (k < NE) {
          const float* wr = W + (size_t)k * NCOL + s3 * NH + d0c + hf * 8;
          const f4v a0 = *(const f4v*)wr;
          const f4v a1 = *(const f4v*)(wr + 4);
          v[0] = a0[0]; v[1] = a0[1]; v[2] = a0[2]; v[3] = a0[3];
          v[4] = a1[0]; v[5] = a1[1]; v[6] = a1[2]; v[7] = a1[3];
        } else {
          #pragma unroll
          for (int j = 0; j < 8; ++j) v[j] = 0.f;
        }
        #pragma unroll
        for (int j = 0; j < 8; ++j)
          wT[(s3 * 16 + hf * 8 + j) * 32 + r3] = f2h(v[j]);
        xbar();
        #pragma unroll
        for (int nt = 0; nt < 2; ++nt) {
          const int cL = (gp + nt) * 16 + (ln & 15);
          xfr[nt][i] = *(const h8v*)((char*)wT + cL * 64 + kgrp * 16);
        }
        xbar();
      }
    }

    lspin(&cnt[0], 4);   // h phase-2 done -> meanTT dead -> XS region free

    // -------- x pipeline: produce zx(n), up to 3 ahead --------
    for (int n = 0; n < NS; ++n) {
      if (n >= 3) lspin(&cnt[3], 4 * (n - 2));   // ring slot n%3 free
      {
        const int xrow = stid >> 3;
        const int tok = gids[(size_t)(b0 + xrow) * NS + n];
        const float* ep_ = p.emb + (size_t)tok * NE;
        #pragma unroll
        for (int j = 0; j < 5; ++j) {
          const int c16 = (stid & 7) + j * 8;
          unsigned short tmp[8];
          if (c16 < 37) {
            const f4v v0 = *(const f4v*)(ep_ + c16 * 8);
            const f4v v1 = *(const f4v*)(ep_ + c16 * 8 + 4);
            tmp[0] = f2h(v0[0]); tmp[1] = f2h(v0[1]); tmp[2] = f2h(v0[2]); tmp[3] = f2h(v0[3]);
            tmp[4] = f2h(v1[0]); tmp[5] = f2h(v1[1]); tmp[6] = f2h(v1[2]); tmp[7] = f2h(v1[3]);
          } else if (c16 == 37) {
            const f4v v0 = *(const f4v*)(ep_ + 296);
            tmp[0] = f2h(v0[0]); tmp[1] = f2h(v0[1]); tmp[2] = f2h(v0[2]); tmp[3] = f2h(v0[3]);
            tmp[4] = 0; tmp[5] = 0; tmp[6] = 0; tmp[7] = 0;
          } else {
            #pragma unroll
            for (int q = 0; q < 8; ++q) tmp[q] = 0;
          }
          *(i4v*)(lds + OFF_XS + xrow * 640 + ((c16 * 16) ^ ((xrow & 7) << 4))) = *(const i4v*)tmp;
        }
      }
      xbar();
      f4v a0 = {0.f, 0.f, 0.f, 0.f}, a1 = {0.f, 0.f, 0.f, 0.f};
      #pragma unroll
      for (int kt = 0; kt < 10; ++kt) {
        h8v a = *(const h8v*)(lds + OFF_XS + arow * 640 + (((kt * 4 + kgrp) * 16) ^ ((arow & 7) << 4)));
        a0 = __builtin_amdgcn_mfma_f32_16x16x32_f16(a, xfr[0][kt], a0, 0, 0, 0);
        a1 = __builtin_amdgcn_mfma_f32_16x16x32_f16(a, xfr[1][kt], a1, 0, 0, 0);
      }
      float* zx = (float*)(lds + OFF_ZX + (n % 3) * 8192);
      #pragma unroll
      for (int rg = 0; rg < 4; ++rg) {
        const int rr = mt * 16 + kgrp * 4 + rg;
        zx[rr * 64 + gp * 16 + (ln & 15)]       = a0[rg];
        zx[rr * 64 + (gp + 1) * 16 + (ln & 15)] = a1[rg];
      }
      if (ln == 0) larrive(&cnt[2]);
      xbar();   // xS reads retired before next gather
    }
  }

  // ---------------- dense head (blocks 0..127, all 512 threads) ----------------
  if (wid < NB) {
    const int b = wid, btq = b >> 5;
    if (tid < 64) {
      const int gsel = tid >> 5;
      const int* f = p.bar + (gsel * 4 + btq) * 32 + (tid & 31);
      int v = ldflag(f);
      while (__ballot(v < NS + 1) != 0ull) { __builtin_amdgcn_s_sleep(1); v = ldflag(f); }
    }
    __syncthreads();

    float a0 = 0.f, a1 = 0.f, a2 = 0.f;
    #pragma unroll
    for (int q = 0; q < 2; ++q) {
      const int kk = q * 512 + tid;
      const int hs = kk >> 9, dim = kk & 511;
      const float* hp = &p.hfin[((size_t)hs * NB + b) * NH + dim];
      const float hv = __hip_atomic_load(hp, __ATOMIC_RELAXED, __HIP_MEMORY_SCOPE_AGENT);
      a0 += hv * p.Wd[kk * 3 + 0];
      a1 += hv * p.Wd[kk * 3 + 1];
      a2 += hv * p.Wd[kk * 3 + 2];
    }
    #pragma unroll
    for (int s = 32; s > 0; s >>= 1) {
      a0 += __shfl_down(a0, s, 64);
      a1 += __shfl_down(a1, s, 64);
      a2 += __shfl_down(a2, s, 64);
    }
    if (ln == 0) { redL[wv][0] = a0; redL[wv][1] = a1; redL[wv][2] = a2; }
    __syncthreads();
    if (tid == 0) {
      float o0 = p.bd[0], o1 = p.bd[1], o2 = p.bd[2];
      #pragma unroll
      for (int w = 0; w < 8; ++w) { o0 += redL[w][0]; o1 += redL[w][1]; o2 += redL[w][2]; }
      p.out[b * 3 + 0] = o0;
      p.out[b * 3 + 1] = o1;
      p.out[b * 3 + 2] = o2;
    }
  }
}

extern "C" void kernel_launch(void* const* d_in, const int* in_sizes, int n_in,
                              void* d_out, int out_size, void* d_ws, size_t ws_size,
                              hipStream_t stream) {
  (void)in_sizes; (void)n_in; (void)out_size; (void)ws_size;
  char* ws = (char*)d_ws;
  Params p;
  p.tids = (const int*)d_in[0];
  p.tlen = (const int*)d_in[1];
  p.lids = (const int*)d_in[2];
  p.llen = (const int*)d_in[3];
  p.rids = (const int*)d_in[4];
  p.rlen = (const int*)d_in[5];
  p.emb  = (const float*)d_in[6];
  p.Wl   = (const float*)d_in[7];
  p.bl   = (const float*)d_in[8];
  p.Wr   = (const float*)d_in[9];
  p.br   = (const float*)d_in[10];
  p.Wd   = (const float*)d_in[11];
  p.bd   = (const float*)d_in[12];
  p.out  = (float*)d_out;
  p.bar  = (int*)ws;                                   // 1024 B
  p.hbuf = (unsigned short*)(ws + 1024);               // 2*2*128*512*2 = 524,288 B
  p.hfin = (float*)(ws + 1024 + 524288);               // 2*128*512*4   = 524,288 B
  hipMemsetAsync(ws, 0, 1024, stream);                 // reset flags each launch
  lstm_all<<<dim3(256), dim3(512), 0, stream>>>(p);
}

// Round 8
// 488.695 us; speedup vs baseline: 1.7682x; 1.3801x over previous
//
#include <hip/hip_runtime.h>

#define NB 128   // batch
#define NS 128   // context seq len
#define NT 12    // target seq len
#define NE 300   // embed dim
#define NH 512   // hidden
#define NCOL 2048  // 4*NH
#define WGSC __HIP_MEMORY_SCOPE_WORKGROUP

typedef _Float16 h8v __attribute__((ext_vector_type(8)));
typedef __attribute__((ext_vector_type(4))) float f4v;
typedef __attribute__((ext_vector_type(4))) int   i4v;

__device__ __forceinline__ unsigned short f2h(float f) {
  union { _Float16 h; unsigned short u; } c; c.h = (_Float16)f; return c.u;
}
__device__ __forceinline__ float sigm(float x) { return 1.f / (1.f + __expf(-x)); }
__device__ __forceinline__ float tanh_(float x) { const float e = __expf(2.f * x); return 1.f - 2.f / (e + 1.f); }

// ---- device-scope UNCACHED (sc1, coherence at IF/L3) exchange primitives ----
__device__ __forceinline__ void st32f_uc(float* p, float v) {
  asm volatile("global_store_dword %0, %1, off sc1" :: "v"(p), "v"(v) : "memory");
}
__device__ __forceinline__ void st32i_uc(int* p, int v) {
  asm volatile("global_store_dword %0, %1, off sc1" :: "v"(p), "v"(v) : "memory");
}
__device__ __forceinline__ int ldflag(const int* p) {
  int v;
  asm volatile("global_load_dword %0, %1, off sc1\n\ts_waitcnt vmcnt(0)" : "=v"(v) : "v"(p) : "memory");
  return v;
}
// 4 x 16B sc1 loads at 256B stride (one h-row slice per lane), one vmcnt
__device__ __forceinline__ void ld4_uc(const char* a, i4v* r) {
  asm volatile(
    "global_load_dwordx4 %0, %4, off sc1\n\t"
    "global_load_dwordx4 %1, %4, off offset:256 sc1\n\t"
    "global_load_dwordx4 %2, %4, off offset:512 sc1\n\t"
    "global_load_dwordx4 %3, %4, off offset:768 sc1\n\t"
    "s_waitcnt vmcnt(0)"
    : "=&v"(r[0]), "=&v"(r[1]), "=&v"(r[2]), "=&v"(r[3])
    : "v"(a) : "memory");
}

struct Params {
  const int *tids, *tlen, *lids, *llen, *rids, *rlen;
  const float *emb, *Wl, *bl, *Wr, *br, *Wd, *bd;
  float* out;
  unsigned short* hbuf;  // [2(pp)][2(side)][NB][NH] f16 (sc1 access)
  float* hfin;           // [2(side)][NB][NH] fp32 (sc1 access)
  int* bar;              // flags: [16 groups] x 4KB page, 16 slots each
};

__device__ __forceinline__ void lspin(int* c, int tgt) {
  while (__hip_atomic_load(c, __ATOMIC_RELAXED, WGSC) < tgt) {}
  __builtin_amdgcn_fence(__ATOMIC_ACQUIRE, "workgroup");
}
__device__ __forceinline__ void larrive(int* c) {
  __hip_atomic_fetch_add(c, 1, __ATOMIC_ACQ_REL, WGSC);
}

// LDS layout (main loop):
//   HS   @ 0     : 16 rows x 1024B f16, XOR-swizzled (h staging)   16384
//   XS   @ 16384 : 16 rows x 640B f16, XOR-swizzled (x staging)    10240
//   ZX   @ 26624 : 3-slot ring, [16][128] f32 (8KB/slot)           24576
//   ZS   @ 51200 : [16][128] f32 gate exchange                      8192
//   HOUT @ 59392 : 2 x [16][32] f16 h-publication staging           2048
// prologue aliases (dead before first conflicting use):
//   meanTT f32[300*16] @ 0..19200 (HS+XS head; freed before x gather, cnt[6])
//   WTH @ 51200 (ZS area, h prologue) ; WTX @ 34816 (ZX slot1, x prologue)
#define OFF_HS   0
#define OFF_XS   16384
#define OFF_ZX   26624
#define OFF_ZS   51200
#define OFF_HOUT 59392
#define OFF_WTH  51200
#define OFF_WTX  34816
#define LDS_SZ   61440

__global__ __launch_bounds__(512, 1) void lstm_all(Params p) {
  __shared__ __align__(16) char lds[LDS_SZ];
  __shared__ int lenL[16];
  __shared__ float redL[8][4];
  __shared__ int cnt[8];   // 0:stage 1:xbar 2:prod 3:cons 4:zsbar 5:pub 6:ph2done 7:hpbar

  const int tid = threadIdx.x;
  const int wid = blockIdx.x;
  if (tid < 8) cnt[tid] = 0;

  // group g = wid&15 (side = g&1, bt = g>>1, 16 rows), dim-block ht = wid>>4 (32 dims)
  const int g = wid & 15, ht = wid >> 4;
  const int side = g & 1, bt = g >> 1;
  const int b0 = bt * 16, d0c = ht * 32;
  const int* lenp = side ? p.rlen : p.llen;
  const int* gids = side ? p.rids : p.lids;
  const float* W = side ? p.Wr : p.Wl;
  const float* bias = side ? p.br : p.bl;
  int* fl = p.bar + g * 1024;          // own 4KB page per group (channel spread)

  const bool isH = tid < 256;          // waves 0-3: h recurrence; 4-7: x pipeline
  const int wv = tid >> 6;
  const int ln = tid & 63;
  const int lwv = isH ? wv : (wv - 4); // role-local wave = GATE index (0..3)
  const int kgrp = ln >> 4;
  const int stid = tid & 255;

  float* meanTT = (float*)lds;
  float* zS = (float*)(lds + OFF_ZS);

  // ---------------- phase 1: mean_t (all 512 threads, transposed [k][16]) ----------------
  {
    const int r = tid >> 5, l32 = tid & 31;
    const int b = b0 + r;
    const int Lt = p.tlen[b];
    const float inv = 1.f / (float)Lt;
    int toks[NT];
    #pragma unroll
    for (int t = 0; t < NT; ++t) toks[t] = p.tids[b * NT + t];
    for (int k = l32; k < NE; k += 32) {
      float s = 0.f;
      #pragma unroll
      for (int t = 0; t < NT; ++t)
        if (t < Lt) s += p.emb[(size_t)toks[t] * NE + k];
      meanTT[k * 16 + r] = s * inv;
    }
    if (tid < 16) lenL[tid] = lenp[b0 + tid];
  }
  __syncthreads();   // the ONLY block-wide barrier before the dense head

  if (isH) {
    // ================= h role (waves 0-3; wave w owns gate w, 32 cols) =================
    const int row_c = stid >> 4;       // cell row 0..15
    const int dloc = stid & 15;        // cell dim pair (dloc, dloc+16)

    // -------- phase 2: z_base = bias + mean @ W[300:600] (fp32, regs) --------
    float zb1[4], zb2[4];
    {
      #pragma unroll
      for (int gq = 0; gq < 4; ++gq) {
        const float* wp = W + (size_t)NE * NCOL + gq * NH + d0c;
        float a1 = bias[gq * NH + d0c + dloc];
        float a2 = bias[gq * NH + d0c + dloc + 16];
        for (int k = 0; k < NE; ++k) {
          const float m = meanTT[k * 16 + row_c];
          a1 += m * wp[(size_t)k * NCOL + dloc];
          a2 += m * wp[(size_t)k * NCOL + dloc + 16];
        }
        zb1[gq] = a1; zb2[gq] = a2;
      }
    }
    if (ln == 0) larrive(&cnt[6]);   // meanTT reads done (per wave) -> frees XS area

    // -------- phase 3h: Wh -> register B-fragments (16 K-tiles x 2 N-tiles) --------
    int he = 0;
    auto hpbar = [&]() {
      ++he;
      if (ln == 0) larrive(&cnt[7]);
      while (__hip_atomic_load(&cnt[7], __ATOMIC_RELAXED, WGSC) < 4 * he) {}
      __builtin_amdgcn_fence(__ATOMIC_ACQUIRE, "workgroup");
    };
    h8v hfr0[16], hfr1[16];
    {
      unsigned short* wT = (unsigned short*)(lds + OFF_WTH);   // [128 cols][32 k]
      const int r3 = stid >> 3;          // k-row 0..31
      const int part = stid & 7;         // 8 col-parts of 16
      const int gate_p = part >> 1, half_p = part & 1;
      for (int i = 0; i < 16; ++i) {
        const int k = 600 + i * 32 + r3;
        const float* wr = W + (size_t)k * NCOL + gate_p * NH + d0c + half_p * 16;
        const f4v a0 = *(const f4v*)wr;
        const f4v a1 = *(const f4v*)(wr + 4);
        const f4v a2 = *(const f4v*)(wr + 8);
        const f4v a3 = *(const f4v*)(wr + 12);
        #pragma unroll
        for (int j = 0; j < 4; ++j) {
          wT[(part * 16 + j) * 32 + r3]      = f2h(a0[j]);
          wT[(part * 16 + 4 + j) * 32 + r3]  = f2h(a1[j]);
          wT[(part * 16 + 8 + j) * 32 + r3]  = f2h(a2[j]);
          wT[(part * 16 + 12 + j) * 32 + r3] = f2h(a3[j]);
        }
        hpbar();
        const int c0 = lwv * 32 + (ln & 15);        // nt0 col of my gate
        hfr0[i] = *(const h8v*)((char*)wT + c0 * 64 + kgrp * 16);
        hfr1[i] = *(const h8v*)((char*)wT + (c0 + 16) * 64 + kgrp * 16);
        hpbar();
      }
    }

    // -------- main recurrence --------
    float cR1 = 0.f, cR2 = 0.f, hR1 = 0.f, hR2 = 0.f;
    const int a_r = ln & 15;                         // A-frag row
    const int srow = lwv * 4 + (ln >> 4);            // staging row for this lane
    for (int t = 0; t < NS; ++t) {
      // 1. zx(t) from ring
      lspin(&cnt[2], 4 * (t + 1));
      const float* zx = (const float*)(lds + OFF_ZX + (t % 3) * 8192);
      f4v acc0, acc1;
      #pragma unroll
      for (int rg = 0; rg < 4; ++rg) {
        const int rr = kgrp * 4 + rg;
        acc0[rg] = zx[rr * 128 + lwv * 32 + (ln & 15)];
        acc1[rg] = zx[rr * 128 + lwv * 32 + 16 + (ln & 15)];
      }
      if (ln == 0) larrive(&cnt[3]);

      // 2. detect peers' h_t, stage 4 rows -> HS, barrier, MFMA
      if (t) {
        {
          int v = 1 << 30;
          const int* f = fl + (ln & 15);
          if (ln < 16) v = ldflag(f);
          while (__ballot(v < t) != 0ull) { if (ln < 16) v = ldflag(f); }
        }
        const char* src = (const char*)(p.hbuf
            + (size_t)(((t & 1) * 2 + side) * NB + b0 + srow) * NH) + (ln & 15) * 16;
        i4v hv[4];
        ld4_uc(src, hv);
        #pragma unroll
        for (int q = 0; q < 4; ++q) {
          const int c16 = (ln & 15) + 16 * q;
          *(i4v*)(lds + OFF_HS + srow * 1024 + ((c16 * 16) ^ ((srow & 7) << 4))) = hv[q];
        }
        if (ln == 0) larrive(&cnt[0]);
        while (__hip_atomic_load(&cnt[0], __ATOMIC_RELAXED, WGSC) < 4 * t) {}
        __builtin_amdgcn_fence(__ATOMIC_ACQUIRE, "workgroup");
        #pragma unroll
        for (int kt = 0; kt < 16; ++kt) {
          h8v a = *(const h8v*)(lds + OFF_HS + a_r * 1024
                                + (((kt * 4 + kgrp) * 16) ^ ((a_r & 7) << 4)));
          acc0 = __builtin_amdgcn_mfma_f32_16x16x32_f16(a, hfr0[kt], acc0, 0, 0, 0);
          acc1 = __builtin_amdgcn_mfma_f32_16x16x32_f16(a, hfr1[kt], acc1, 0, 0, 0);
        }
      }

      // 3. gate exchange (wave w -> zS cols of gate w)
      #pragma unroll
      for (int rg = 0; rg < 4; ++rg) {
        const int rr = kgrp * 4 + rg;
        zS[rr * 128 + lwv * 32 + (ln & 15)]      = acc0[rg];
        zS[rr * 128 + lwv * 32 + 16 + (ln & 15)] = acc1[rg];
      }
      if (ln == 0) larrive(&cnt[4]);
      while (__hip_atomic_load(&cnt[4], __ATOMIC_RELAXED, WGSC) < 4 * (t + 1)) {}
      __builtin_amdgcn_fence(__ATOMIC_ACQUIRE, "workgroup");

      // 4. cell update (row_c, dims dloc & dloc+16); h -> HOUT[t&1]
      {
        unsigned short* hOut = (unsigned short*)(lds + OFF_HOUT + (t & 1) * 1024);
        const float* zr = zS + row_c * 128;
        float zi = zr[0 * 32 + dloc] + zb1[0], zj = zr[1 * 32 + dloc] + zb1[1];
        float zf = zr[2 * 32 + dloc] + zb1[2], zo = zr[3 * 32 + dloc] + zb1[3];
        float ig = sigm(zi), jg = tanh_(zj), fg = sigm(zf + 1.f), og = sigm(zo);
        float cn = fg * cR1 + ig * jg;
        float hn = og * tanh_(cn);
        if (t < lenL[row_c]) { cR1 = cn; hR1 = hn; }
        hOut[row_c * 32 + dloc] = f2h(hR1);
        zi = zr[0 * 32 + dloc + 16] + zb2[0]; zj = zr[1 * 32 + dloc + 16] + zb2[1];
        zf = zr[2 * 32 + dloc + 16] + zb2[2]; zo = zr[3 * 32 + dloc + 16] + zb2[3];
        ig = sigm(zi); jg = tanh_(zj); fg = sigm(zf + 1.f); og = sigm(zo);
        cn = fg * cR2 + ig * jg; hn = og * tanh_(cn);
        if (t < lenL[row_c]) { cR2 = cn; hR2 = hn; }
        hOut[row_c * 32 + dloc + 16] = f2h(hR2);
      }

      // 5. publish (rotating wave t&3); others continue immediately
      if (ln == 0) larrive(&cnt[5]);
      if (lwv == (t & 3)) {
        while (__hip_atomic_load(&cnt[5], __ATOMIC_RELAXED, WGSC) < 4 * (t + 1)) {}
        __builtin_amdgcn_fence(__ATOMIC_ACQUIRE, "workgroup");
        const int prow = ln >> 2, ppart = ln & 3;
        i4v hv = *(const i4v*)(lds + OFF_HOUT + (t & 1) * 1024 + prow * 64 + ppart * 16);
        unsigned short* dst = p.hbuf
            + (size_t)((((t + 1) & 1) * 2 + side) * NB + b0 + prow) * NH + d0c + ppart * 8;
        asm volatile("global_store_dwordx4 %0, %1, off sc1\n\ts_waitcnt vmcnt(0)"
                     :: "v"(dst), "v"(hv) : "memory");
        if (ln == 0) st32i_uc(fl + ht, t + 1);
      }
    }

    // -------- epilogue: final h -> hfin (sc1), flag NS+1 --------
    st32f_uc(&p.hfin[((size_t)side * NB + b0 + row_c) * NH + d0c + dloc], hR1);
    st32f_uc(&p.hfin[((size_t)side * NB + b0 + row_c) * NH + d0c + dloc + 16], hR2);
    asm volatile("s_waitcnt vmcnt(0)" ::: "memory");
    if (ln == 0) larrive(&cnt[5]);
    if (lwv == 0) {
      while (__hip_atomic_load(&cnt[5], __ATOMIC_RELAXED, WGSC) < 4 * NS + 4) {}
      if (ln == 0) st32i_uc(fl + ht, NS + 1);
    }
  } else {
    // ================= x role (waves 4-7; wave owns gate lwv) =================
    int xe = 0;
    auto xbar = [&]() {
      ++xe;
      if (ln == 0) larrive(&cnt[1]);
      while (__hip_atomic_load(&cnt[1], __ATOMIC_RELAXED, WGSC) < 4 * xe) {}
      __builtin_amdgcn_fence(__ATOMIC_ACQUIRE, "workgroup");
    };

    // -------- phase 3x: Wx -> register B-fragments (10 K-tiles x 2 N-tiles) --------
    h8v xfr0[10], xfr1[10];
    {
      unsigned short* wT = (unsigned short*)(lds + OFF_WTX);   // [128 cols][32 k]
      const int r3 = stid >> 3, part = stid & 7;
      const int gate_p = part >> 1, half_p = part & 1;
      for (int i = 0; i < 10; ++i) {
        const int k = i * 32 + r3;
        float v[16];
        if (k < NE) {
          const float* wr = W + (size_t)k * NCOL + gate_p * NH + d0c + half_p * 16;
          const f4v a0 = *(const f4v*)wr;
          const f4v a1 = *(const f4v*)(wr + 4);
          const f4v a2 = *(const f4v*)(wr + 8);
          const f4v a3 = *(const f4v*)(wr + 12);
          #pragma unroll
          for (int j = 0; j < 4; ++j) {
            v[j] = a0[j]; v[4 + j] = a1[j]; v[8 + j] = a2[j]; v[12 + j] = a3[j];
          }
        } else {
          #pragma unroll
          for (int j = 0; j < 16; ++j) v[j] = 0.f;
        }
        #pragma unroll
        for (int j = 0; j < 16; ++j)
          wT[(part * 16 + j) * 32 + r3] = f2h(v[j]);
        xbar();
        const int c0 = lwv * 32 + (ln & 15);
        xfr0[i] = *(const h8v*)((char*)wT + c0 * 64 + kgrp * 16);
        xfr1[i] = *(const h8v*)((char*)wT + (c0 + 16) * 64 + kgrp * 16);
        xbar();
      }
    }

    lspin(&cnt[6], 4);   // h phase-2 done -> meanTT dead -> XS free

    // -------- x pipeline: produce zx(n) = x_n @ Wx, up to 3 ahead --------
    for (int n = 0; n < NS; ++n) {
      if (n >= 3) lspin(&cnt[3], 4 * (n - 2));   // ring slot n%3 free
      {
        const int xrow = stid >> 4;              // 16 rows, 16 lanes each
        const int tok = gids[(size_t)(b0 + xrow) * NS + n];
        const float* ep_ = p.emb + (size_t)tok * NE;
        #pragma unroll
        for (int j = 0; j < 3; ++j) {
          const int c16 = (stid & 15) + j * 16;
          if (c16 < 40) {
            unsigned short tmp[8];
            if (c16 < 37) {
              const f4v v0 = *(const f4v*)(ep_ + c16 * 8);
              const f4v v1 = *(const f4v*)(ep_ + c16 * 8 + 4);
              tmp[0] = f2h(v0[0]); tmp[1] = f2h(v0[1]); tmp[2] = f2h(v0[2]); tmp[3] = f2h(v0[3]);
              tmp[4] = f2h(v1[0]); tmp[5] = f2h(v1[1]); tmp[6] = f2h(v1[2]); tmp[7] = f2h(v1[3]);
            } else if (c16 == 37) {
              const f4v v0 = *(const f4v*)(ep_ + 296);
              tmp[0] = f2h(v0[0]); tmp[1] = f2h(v0[1]); tmp[2] = f2h(v0[2]); tmp[3] = f2h(v0[3]);
              tmp[4] = 0; tmp[5] = 0; tmp[6] = 0; tmp[7] = 0;
            } else {
              #pragma unroll
              for (int q = 0; q < 8; ++q) tmp[q] = 0;
            }
            *(i4v*)(lds + OFF_XS + xrow * 640 + ((c16 * 16) ^ ((xrow & 7) << 4))) = *(const i4v*)tmp;
          }
        }
      }
      xbar();
      f4v a0 = {0.f, 0.f, 0.f, 0.f}, a1 = {0.f, 0.f, 0.f, 0.f};
      const int a_r = ln & 15;
      #pragma unroll
      for (int kt = 0; kt < 10; ++kt) {
        h8v a = *(const h8v*)(lds + OFF_XS + a_r * 640
                              + (((kt * 4 + kgrp) * 16) ^ ((a_r & 7) << 4)));
        a0 = __builtin_amdgcn_mfma_f32_16x16x32_f16(a, xfr0[kt], a0, 0, 0, 0);
        a1 = __builtin_amdgcn_mfma_f32_16x16x32_f16(a, xfr1[kt], a1, 0, 0, 0);
      }
      float* zx = (float*)(lds + OFF_ZX + (n % 3) * 8192);
      #pragma unroll
      for (int rg = 0; rg < 4; ++rg) {
        const int rr = kgrp * 4 + rg;
        zx[rr * 128 + lwv * 32 + (ln & 15)]      = a0[rg];
        zx[rr * 128 + lwv * 32 + 16 + (ln & 15)] = a1[rg];
      }
      if (ln == 0) larrive(&cnt[2]);
      xbar();   // xS reads retired before next gather
    }
  }

  // ---------------- dense head (blocks 0..127, all 512 threads) ----------------
  if (wid < NB) {
    const int b = wid, bth = b >> 4;
    if (tid < 32) {
      const int gh = (bth << 1) + (tid >> 4);    // side = tid>>4
      const int* f = p.bar + gh * 1024 + (tid & 15);
      int v = ldflag(f);
      while (__ballot(v < NS + 1) != 0ull) { __builtin_amdgcn_s_sleep(2); v = ldflag(f); }
    }
    __syncthreads();

    float a0 = 0.f, a1 = 0.f, a2 = 0.f;
    #pragma unroll
    for (int q = 0; q < 2; ++q) {
      const int kk = q * 512 + tid;
      const int hs = kk >> 9, dim = kk & 511;
      const float* hp = &p.hfin[((size_t)hs * NB + b) * NH + dim];
      const float hv = __hip_atomic_load(hp, __ATOMIC_RELAXED, __HIP_MEMORY_SCOPE_AGENT);
      a0 += hv * p.Wd[kk * 3 + 0];
      a1 += hv * p.Wd[kk * 3 + 1];
      a2 += hv * p.Wd[kk * 3 + 2];
    }
    #pragma unroll
    for (int s = 32; s > 0; s >>= 1) {
      a0 += __shfl_down(a0, s, 64);
      a1 += __shfl_down(a1, s, 64);
      a2 += __shfl_down(a2, s, 64);
    }
    if (ln == 0) { redL[wv][0] = a0; redL[wv][1] = a1; redL[wv][2] = a2; }
    __syncthreads();
    if (tid == 0) {
      float o0 = p.bd[0], o1 = p.bd[1], o2 = p.bd[2];
      #pragma unroll
      for (int w = 0; w < 8; ++w) { o0 += redL[w][0]; o1 += redL[w][1]; o2 += redL[w][2]; }
      p.out[b * 3 + 0] = o0;
      p.out[b * 3 + 1] = o1;
      p.out[b * 3 + 2] = o2;
    }
  }
}

extern "C" void kernel_launch(void* const* d_in, const int* in_sizes, int n_in,
                              void* d_out, int out_size, void* d_ws, size_t ws_size,
                              hipStream_t stream) {
  (void)in_sizes; (void)n_in; (void)out_size; (void)ws_size;
  char* ws = (char*)d_ws;
  Params p;
  p.tids = (const int*)d_in[0];
  p.tlen = (const int*)d_in[1];
  p.lids = (const int*)d_in[2];
  p.llen = (const int*)d_in[3];
  p.rids = (const int*)d_in[4];
  p.rlen = (const int*)d_in[5];
  p.emb  = (const float*)d_in[6];
  p.Wl   = (const float*)d_in[7];
  p.bl   = (const float*)d_in[8];
  p.Wr   = (const float*)d_in[9];
  p.br   = (const float*)d_in[10];
  p.Wd   = (const float*)d_in[11];
  p.bd   = (const float*)d_in[12];
  p.out  = (float*)d_out;
  p.bar  = (int*)ws;                                   // 16 groups x 4KB = 65,536 B
  p.hbuf = (unsigned short*)(ws + 65536);              // 2*2*128*512*2 = 524,288 B
  p.hfin = (float*)(ws + 65536 + 524288);              // 2*128*512*4   = 524,288 B
  hipMemsetAsync(ws, 0, 65536, stream);                // reset flags each launch
  lstm_all<<<dim3(256), dim3(512), 0, stream>>>(p);
}

// Round 9
// 435.149 us; speedup vs baseline: 1.9858x; 1.1231x over previous
//
#include <hip/hip_runtime.h>

#define NB 128   // batch
#define NS 128   // context seq len
#define NT 12    // target seq len
#define NE 300   // embed dim
#define NH 512   // hidden
#define NCOL 2048  // 4*NH
#define WGSC __HIP_MEMORY_SCOPE_WORKGROUP

typedef _Float16 h8v __attribute__((ext_vector_type(8)));
typedef __attribute__((ext_vector_type(4))) float f4v;
typedef __attribute__((ext_vector_type(4))) int   i4v;

__device__ __forceinline__ unsigned short f2h(float f) {
  union { _Float16 h; unsigned short u; } c; c.h = (_Float16)f; return c.u;
}
__device__ __forceinline__ float sigm(float x) { return 1.f / (1.f + __expf(-x)); }
__device__ __forceinline__ float tanh_(float x) { const float e = __expf(2.f * x); return 1.f - 2.f / (e + 1.f); }

// pack two f16 h-values into a dword, stealing each mantissa LSB for a 2-bit step tag
__device__ __forceinline__ unsigned packh(float a, float b, int tag) {
  unsigned lo = f2h(a), hi = f2h(b);
  lo = (lo & ~1u) | (unsigned)(tag & 1);
  hi = (hi & ~1u) | (unsigned)((tag >> 1) & 1);
  return lo | (hi << 16);
}

// ---- device-scope UNCACHED (sc1, coherence at IF/L3) primitives ----
__device__ __forceinline__ void st32f_uc(float* p, float v) {
  asm volatile("global_store_dword %0, %1, off sc1" :: "v"(p), "v"(v) : "memory");
}
__device__ __forceinline__ void st32i_uc(int* p, int v) {
  asm volatile("global_store_dword %0, %1, off sc1" :: "v"(p), "v"(v) : "memory");
}
__device__ __forceinline__ void st32u_uc(unsigned* p, unsigned v) {
  asm volatile("global_store_dword %0, %1, off sc1" :: "v"(p), "v"(v) : "memory");
}
__device__ __forceinline__ int ldflag(const int* p) {
  int v;
  asm volatile("global_load_dword %0, %1, off sc1\n\ts_waitcnt vmcnt(0)" : "=v"(v) : "v"(p) : "memory");
  return v;
}
// 4 x 16B sc1 loads of one contiguous 64B chunk, one vmcnt
__device__ __forceinline__ void ld64_uc(const char* a, i4v* r) {
  asm volatile(
    "global_load_dwordx4 %0, %4, off sc1\n\t"
    "global_load_dwordx4 %1, %4, off offset:16 sc1\n\t"
    "global_load_dwordx4 %2, %4, off offset:32 sc1\n\t"
    "global_load_dwordx4 %3, %4, off offset:48 sc1\n\t"
    "s_waitcnt vmcnt(0)"
    : "=&v"(r[0]), "=&v"(r[1]), "=&v"(r[2]), "=&v"(r[3])
    : "v"(a) : "memory");
}

struct Params {
  const int *tids, *tlen, *lids, *llen, *rids, *rlen;
  const float *emb, *Wl, *bl, *Wr, *br, *Wd, *bd;
  float* out;
  unsigned short* hbuf;  // [2(pp)][2(side)][NB][NH] f16 tagged (sc1 access; zeroed each launch)
  float* hfin;           // [2(side)][NB][NH] fp32 (sc1 access)
  int* bar;              // flags: [16 groups] x 4KB page (epilogue only)
};

__device__ __forceinline__ void lspin(int* c, int tgt) {
  while (__hip_atomic_load(c, __ATOMIC_RELAXED, WGSC) < tgt) {}
  __builtin_amdgcn_fence(__ATOMIC_ACQUIRE, "workgroup");
}
__device__ __forceinline__ void larrive(int* c) {
  __hip_atomic_fetch_add(c, 1, __ATOMIC_ACQ_REL, WGSC);
}

// LDS layout (main loop):
//   HS   @ 0     : 16 rows x 1024B f16, XOR-swizzled (h staging)   16384
//   XS   @ 16384 : 16 rows x 640B f16, XOR-swizzled (x staging)    10240
//   ZX   @ 26624 : 3-slot ring, [16][128] f32 (8KB/slot)           24576
//   ZS   @ 51200 : [16][128] f32 gate exchange                      8192
// prologue aliases (dead before first conflicting use):
//   meanTT f32[300*16] @ 0..19200 ; WTH @ 51200 (ZS) ; WTX @ 34816 (ZX slot1)
#define OFF_HS   0
#define OFF_XS   16384
#define OFF_ZX   26624
#define OFF_ZS   51200
#define OFF_WTH  51200
#define OFF_WTX  34816
#define LDS_SZ   59392

__global__ __launch_bounds__(512, 1) void lstm_all(Params p) {
  __shared__ __align__(16) char lds[LDS_SZ];
  __shared__ int lenL[16];
  __shared__ float redL[8][4];
  __shared__ int cnt[8];   // 0:stage 1:xbar 2:prod 3:cons 4:zsbar 5:epi 6:ph2done 7:hpbar

  const int tid = threadIdx.x;
  const int wid = blockIdx.x;
  if (tid < 8) cnt[tid] = 0;

  // group g = wid&15 (side=g&1, bt=g>>1: 16 batch rows), dim-block ht = wid>>4 (32 dims)
  const int g = wid & 15, ht = wid >> 4;
  const int side = g & 1, bt = g >> 1;
  const int b0 = bt * 16, d0c = ht * 32;
  const int* lenp = side ? p.rlen : p.llen;
  const int* gids = side ? p.rids : p.lids;
  const float* W = side ? p.Wr : p.Wl;
  const float* bias = side ? p.br : p.bl;
  int* fl = p.bar + g * 1024;

  const bool isH = tid < 256;          // waves 0-3: h recurrence; 4-7: x pipeline
  const int wv = tid >> 6;
  const int ln = tid & 63;
  const int lwv = isH ? wv : (wv - 4); // role-local wave = GATE index (0..3)
  const int kgrp = ln >> 4;
  const int stid = tid & 255;

  float* meanTT = (float*)lds;
  float* zS = (float*)(lds + OFF_ZS);

  // ---------------- phase 1: mean_t (all 512 threads, transposed [k][16]) ----------------
  {
    const int r = tid >> 5, l32 = tid & 31;
    const int b = b0 + r;
    const int Lt = p.tlen[b];
    const float inv = 1.f / (float)Lt;
    int toks[NT];
    #pragma unroll
    for (int t = 0; t < NT; ++t) toks[t] = p.tids[b * NT + t];
    for (int k = l32; k < NE; k += 32) {
      float s = 0.f;
      #pragma unroll
      for (int t = 0; t < NT; ++t)
        if (t < Lt) s += p.emb[(size_t)toks[t] * NE + k];
      meanTT[k * 16 + r] = s * inv;
    }
    if (tid < 16) lenL[tid] = lenp[b0 + tid];
  }
  __syncthreads();   // the ONLY block-wide barrier before the dense head

  if (isH) {
    // ================= h role (waves 0-3; wave w owns gate w) =================
    const int row_c = stid >> 4;       // cell row 0..15 (wave w: rows 4w..4w+3)
    const int m = stid & 15;           // cell dim pair (2m, 2m+1)

    // -------- phase 2: z_base = bias + mean @ W[300:600] (fp32, regs) --------
    float zb1[4], zb2[4];
    {
      #pragma unroll
      for (int gq = 0; gq < 4; ++gq) {
        const float* wp = W + (size_t)NE * NCOL + gq * NH + d0c;
        float a1 = bias[gq * NH + d0c + 2 * m];
        float a2 = bias[gq * NH + d0c + 2 * m + 1];
        for (int k = 0; k < NE; ++k) {
          const float mv = meanTT[k * 16 + row_c];
          a1 += mv * wp[(size_t)k * NCOL + 2 * m];
          a2 += mv * wp[(size_t)k * NCOL + 2 * m + 1];
        }
        zb1[gq] = a1; zb2[gq] = a2;
      }
    }
    if (ln == 0) larrive(&cnt[6]);   // meanTT reads done -> frees XS area

    // -------- phase 3h: Wh -> register B-fragments (16 K-tiles x 2 N-tiles) --------
    int he = 0;
    auto hpbar = [&]() {
      ++he;
      if (ln == 0) larrive(&cnt[7]);
      while (__hip_atomic_load(&cnt[7], __ATOMIC_RELAXED, WGSC) < 4 * he) {}
      __builtin_amdgcn_fence(__ATOMIC_ACQUIRE, "workgroup");
    };
    h8v hfr0[16], hfr1[16];
    {
      unsigned short* wT = (unsigned short*)(lds + OFF_WTH);   // [128 cols][32 k]
      const int r3 = stid >> 3;
      const int part = stid & 7;
      const int gate_p = part >> 1, half_p = part & 1;
      for (int i = 0; i < 16; ++i) {
        const int k = 600 + i * 32 + r3;
        const float* wr = W + (size_t)k * NCOL + gate_p * NH + d0c + half_p * 16;
        const f4v a0 = *(const f4v*)wr;
        const f4v a1 = *(const f4v*)(wr + 4);
        const f4v a2 = *(const f4v*)(wr + 8);
        const f4v a3 = *(const f4v*)(wr + 12);
        #pragma unroll
        for (int j = 0; j < 4; ++j) {
          wT[(part * 16 + j) * 32 + r3]      = f2h(a0[j]);
          wT[(part * 16 + 4 + j) * 32 + r3]  = f2h(a1[j]);
          wT[(part * 16 + 8 + j) * 32 + r3]  = f2h(a2[j]);
          wT[(part * 16 + 12 + j) * 32 + r3] = f2h(a3[j]);
        }
        hpbar();
        const int c0 = lwv * 32 + (ln & 15);
        hfr0[i] = *(const h8v*)((char*)wT + c0 * 64 + kgrp * 16);
        hfr1[i] = *(const h8v*)((char*)wT + (c0 + 16) * 64 + kgrp * 16);
        hpbar();
      }
    }

    // -------- main recurrence --------
    float cR1 = 0.f, cR2 = 0.f, hR1 = 0.f, hR2 = 0.f;
    const int a_r = ln & 15;                         // A-frag row
    const int srow = stid >> 4;                      // staging row (== row_c)
    const int schk = stid & 15;                      // staging 64B chunk
    for (int t = 0; t < NS; ++t) {
      // 1. zx(t) from ring
      lspin(&cnt[2], 4 * (t + 1));
      const float* zx = (const float*)(lds + OFF_ZX + (t % 3) * 8192);
      f4v acc0, acc1;
      #pragma unroll
      for (int rg = 0; rg < 4; ++rg) {
        const int rr = kgrp * 4 + rg;
        acc0[rg] = zx[rr * 128 + lwv * 32 + (ln & 15)];
        acc1[rg] = zx[rr * 128 + lwv * 32 + 16 + (ln & 15)];
      }
      if (ln == 0) larrive(&cnt[3]);

      // 2. poll-validate h_t (tag = t&3 embedded in data), stage -> HS, barrier, MFMA
      if (t) {
        const char* src = (const char*)(p.hbuf
            + (size_t)(((t & 1) * 2 + side) * NB + b0 + srow) * NH + schk * 32);
        const unsigned exp32 = ((unsigned)(t & 1)) | (((unsigned)((t >> 1) & 1)) << 16);
        i4v v[4];
        for (;;) {
          ld64_uc(src, v);
          unsigned bad = 0;
          #pragma unroll
          for (int q = 0; q < 4; ++q)
            #pragma unroll
            for (int j = 0; j < 4; ++j)
              bad |= (((unsigned)v[q][j]) ^ exp32) & 0x00010001u;
          if (!bad) break;
        }
        #pragma unroll
        for (int q = 0; q < 4; ++q) {
          const int c16 = schk * 4 + q;
          *(i4v*)(lds + OFF_HS + srow * 1024 + ((c16 * 16) ^ ((srow & 7) << 4))) = v[q];
        }
        if (ln == 0) larrive(&cnt[0]);
        while (__hip_atomic_load(&cnt[0], __ATOMIC_RELAXED, WGSC) < 4 * t) {}
        __builtin_amdgcn_fence(__ATOMIC_ACQUIRE, "workgroup");
        #pragma unroll
        for (int kt = 0; kt < 16; ++kt) {
          h8v a = *(const h8v*)(lds + OFF_HS + a_r * 1024
                                + (((kt * 4 + kgrp) * 16) ^ ((a_r & 7) << 4)));
          acc0 = __builtin_amdgcn_mfma_f32_16x16x32_f16(a, hfr0[kt], acc0, 0, 0, 0);
          acc1 = __builtin_amdgcn_mfma_f32_16x16x32_f16(a, hfr1[kt], acc1, 0, 0, 0);
        }
      }

      // 3. gate exchange (wave w -> zS cols of gate w)
      #pragma unroll
      for (int rg = 0; rg < 4; ++rg) {
        const int rr = kgrp * 4 + rg;
        zS[rr * 128 + lwv * 32 + (ln & 15)]      = acc0[rg];
        zS[rr * 128 + lwv * 32 + 16 + (ln & 15)] = acc1[rg];
      }
      if (ln == 0) larrive(&cnt[4]);
      while (__hip_atomic_load(&cnt[4], __ATOMIC_RELAXED, WGSC) < 4 * (t + 1)) {}
      __builtin_amdgcn_fence(__ATOMIC_ACQUIRE, "workgroup");

      // 4. cell update (row_c, dims 2m/2m+1); tagged coalesced dword store, NO drain/flag
      {
        const float* zr = zS + row_c * 128;
        float zi = zr[0 * 32 + 2 * m] + zb1[0], zj = zr[1 * 32 + 2 * m] + zb1[1];
        float zf = zr[2 * 32 + 2 * m] + zb1[2], zo = zr[3 * 32 + 2 * m] + zb1[3];
        float ig = sigm(zi), jg = tanh_(zj), fg = sigm(zf + 1.f), og = sigm(zo);
        float cn = fg * cR1 + ig * jg;
        float hn = og * tanh_(cn);
        if (t < lenL[row_c]) { cR1 = cn; hR1 = hn; }
        zi = zr[0 * 32 + 2 * m + 1] + zb2[0]; zj = zr[1 * 32 + 2 * m + 1] + zb2[1];
        zf = zr[2 * 32 + 2 * m + 1] + zb2[2]; zo = zr[3 * 32 + 2 * m + 1] + zb2[3];
        ig = sigm(zi); jg = tanh_(zj); fg = sigm(zf + 1.f); og = sigm(zo);
        cn = fg * cR2 + ig * jg; hn = og * tanh_(cn);
        if (t < lenL[row_c]) { cR2 = cn; hR2 = hn; }
        unsigned pk = packh(hR1, hR2, (t + 1) & 3);
        unsigned* dst = (unsigned*)p.hbuf
            + ((size_t)((((t + 1) & 1) * 2 + side) * NB + b0 + row_c) * (NH / 2)) + d0c / 2 + m;
        st32u_uc(dst, pk);
      }
    }

    // -------- epilogue: final h -> hfin (sc1, clean fp32), then flag NS+1 --------
    st32f_uc(&p.hfin[((size_t)side * NB + b0 + row_c) * NH + d0c + 2 * m], hR1);
    st32f_uc(&p.hfin[((size_t)side * NB + b0 + row_c) * NH + d0c + 2 * m + 1], hR2);
    asm volatile("s_waitcnt vmcnt(0)" ::: "memory");
    if (ln == 0) larrive(&cnt[5]);
    if (lwv == 0) {
      while (__hip_atomic_load(&cnt[5], __ATOMIC_RELAXED, WGSC) < 4) {}
      if (ln == 0) st32i_uc(fl + ht, NS + 1);
    }
  } else {
    // ================= x role (waves 4-7; wave owns gate lwv) =================
    int xe = 0;
    auto xbar = [&]() {
      ++xe;
      if (ln == 0) larrive(&cnt[1]);
      while (__hip_atomic_load(&cnt[1], __ATOMIC_RELAXED, WGSC) < 4 * xe) {}
      __builtin_amdgcn_fence(__ATOMIC_ACQUIRE, "workgroup");
    };

    // -------- phase 3x: Wx -> register B-fragments (10 K-tiles x 2 N-tiles) --------
    h8v xfr0[10], xfr1[10];
    {
      unsigned short* wT = (unsigned short*)(lds + OFF_WTX);   // [128 cols][32 k]
      const int r3 = stid >> 3, part = stid & 7;
      const int gate_p = part >> 1, half_p = part & 1;
      for (int i = 0; i < 10; ++i) {
        const int k = i * 32 + r3;
        float v[16];
        if (k < NE) {
          const float* wr = W + (size_t)k * NCOL + gate_p * NH + d0c + half_p * 16;
          const f4v a0 = *(const f4v*)wr;
          const f4v a1 = *(const f4v*)(wr + 4);
          const f4v a2 = *(const f4v*)(wr + 8);
          const f4v a3 = *(const f4v*)(wr + 12);
          #pragma unroll
          for (int j = 0; j < 4; ++j) {
            v[j] = a0[j]; v[4 + j] = a1[j]; v[8 + j] = a2[j]; v[12 + j] = a3[j];
          }
        } else {
          #pragma unroll
          for (int j = 0; j < 16; ++j) v[j] = 0.f;
        }
        #pragma unroll
        for (int j = 0; j < 16; ++j)
          wT[(part * 16 + j) * 32 + r3] = f2h(v[j]);
        xbar();
        const int c0 = lwv * 32 + (ln & 15);
        xfr0[i] = *(const h8v*)((char*)wT + c0 * 64 + kgrp * 16);
        xfr1[i] = *(const h8v*)((char*)wT + (c0 + 16) * 64 + kgrp * 16);
        xbar();
      }
    }

    lspin(&cnt[6], 4);   // h phase-2 done -> meanTT dead -> XS free

    // -------- x pipeline: produce zx(n) = x_n @ Wx, up to 3 ahead --------
    for (int n = 0; n < NS; ++n) {
      if (n >= 3) lspin(&cnt[3], 4 * (n - 2));   // ring slot n%3 free
      {
        const int xrow = stid >> 4;              // 16 rows, 16 lanes each
        const int tok = gids[(size_t)(b0 + xrow) * NS + n];
        const float* ep_ = p.emb + (size_t)tok * NE;
        #pragma unroll
        for (int j = 0; j < 3; ++j) {
          const int c16 = (stid & 15) + j * 16;
          if (c16 < 40) {
            unsigned short tmp[8];
            if (c16 < 37) {
              const f4v v0 = *(const f4v*)(ep_ + c16 * 8);
              const f4v v1 = *(const f4v*)(ep_ + c16 * 8 + 4);
              tmp[0] = f2h(v0[0]); tmp[1] = f2h(v0[1]); tmp[2] = f2h(v0[2]); tmp[3] = f2h(v0[3]);
              tmp[4] = f2h(v1[0]); tmp[5] = f2h(v1[1]); tmp[6] = f2h(v1[2]); tmp[7] = f2h(v1[3]);
            } else if (c16 == 37) {
              const f4v v0 = *(const f4v*)(ep_ + 296);
              tmp[0] = f2h(v0[0]); tmp[1] = f2h(v0[1]); tmp[2] = f2h(v0[2]); tmp[3] = f2h(v0[3]);
              tmp[4] = 0; tmp[5] = 0; tmp[6] = 0; tmp[7] = 0;
            } else {
              #pragma unroll
              for (int q = 0; q < 8; ++q) tmp[q] = 0;
            }
            *(i4v*)(lds + OFF_XS + xrow * 640 + ((c16 * 16) ^ ((xrow & 7) << 4))) = *(const i4v*)tmp;
          }
        }
      }
      xbar();
      f4v a0 = {0.f, 0.f, 0.f, 0.f}, a1 = {0.f, 0.f, 0.f, 0.f};
      const int a_r = ln & 15;
      #pragma unroll
      for (int kt = 0; kt < 10; ++kt) {
        h8v a = *(const h8v*)(lds + OFF_XS + a_r * 640
                              + (((kt * 4 + kgrp) * 16) ^ ((a_r & 7) << 4)));
        a0 = __builtin_amdgcn_mfma_f32_16x16x32_f16(a, xfr0[kt], a0, 0, 0, 0);
        a1 = __builtin_amdgcn_mfma_f32_16x16x32_f16(a, xfr1[kt], a1, 0, 0, 0);
      }
      float* zx = (float*)(lds + OFF_ZX + (n % 3) * 8192);
      #pragma unroll
      for (int rg = 0; rg < 4; ++rg) {
        const int rr = kgrp * 4 + rg;
        zx[rr * 128 + lwv * 32 + (ln & 15)]      = a0[rg];
        zx[rr * 128 + lwv * 32 + 16 + (ln & 15)] = a1[rg];
      }
      if (ln == 0) larrive(&cnt[2]);
      xbar();   // xS reads retired before next gather
    }
  }

  // ---------------- dense head (blocks 0..127, all 512 threads) ----------------
  if (wid < NB) {
    const int b = wid, bth = b >> 4;
    if (tid < 32) {
      const int gh = (bth << 1) + (tid >> 4);    // side = tid>>4
      const int* f = p.bar + gh * 1024 + (tid & 15);
      int v = ldflag(f);
      while (__ballot(v < NS + 1) != 0ull) { __builtin_amdgcn_s_sleep(2); v = ldflag(f); }
    }
    __syncthreads();

    float a0 = 0.f, a1 = 0.f, a2 = 0.f;
    #pragma unroll
    for (int q = 0; q < 2; ++q) {
      const int kk = q * 512 + tid;
      const int hs = kk >> 9, dim = kk & 511;
      const float* hp = &p.hfin[((size_t)hs * NB + b) * NH + dim];
      const float hv = __hip_atomic_load(hp, __ATOMIC_RELAXED, __HIP_MEMORY_SCOPE_AGENT);
      a0 += hv * p.Wd[kk * 3 + 0];
      a1 += hv * p.Wd[kk * 3 + 1];
      a2 += hv * p.Wd[kk * 3 + 2];
    }
    #pragma unroll
    for (int s = 32; s > 0; s >>= 1) {
      a0 += __shfl_down(a0, s, 64);
      a1 += __shfl_down(a1, s, 64);
      a2 += __shfl_down(a2, s, 64);
    }
    if (ln == 0) { redL[wv][0] = a0; redL[wv][1] = a1; redL[wv][2] = a2; }
    __syncthreads();
    if (tid == 0) {
      float o0 = p.bd[0], o1 = p.bd[1], o2 = p.bd[2];
      #pragma unroll
      for (int w = 0; w < 8; ++w) { o0 += redL[w][0]; o1 += redL[w][1]; o2 += redL[w][2]; }
      p.out[b * 3 + 0] = o0;
      p.out[b * 3 + 1] = o1;
      p.out[b * 3 + 2] = o2;
    }
  }
}

extern "C" void kernel_launch(void* const* d_in, const int* in_sizes, int n_in,
                              void* d_out, int out_size, void* d_ws, size_t ws_size,
                              hipStream_t stream) {
  (void)in_sizes; (void)n_in; (void)out_size; (void)ws_size;
  char* ws = (char*)d_ws;
  Params p;
  p.tids = (const int*)d_in[0];
  p.tlen = (const int*)d_in[1];
  p.lids = (const int*)d_in[2];
  p.llen = (const int*)d_in[3];
  p.rids = (const int*)d_in[4];
  p.rlen = (const int*)d_in[5];
  p.emb  = (const float*)d_in[6];
  p.Wl   = (const float*)d_in[7];
  p.bl   = (const float*)d_in[8];
  p.Wr   = (const float*)d_in[9];
  p.br   = (const float*)d_in[10];
  p.Wd   = (const float*)d_in[11];
  p.bd   = (const float*)d_in[12];
  p.out  = (float*)d_out;
  p.bar  = (int*)ws;                                   // 16 x 4KB = 65,536 B
  p.hbuf = (unsigned short*)(ws + 65536);              // 2*2*128*512*2 = 524,288 B
  p.hfin = (float*)(ws + 65536 + 524288);              // 2*128*512*4   = 524,288 B
  // zero flags AND hbuf (tag-poison safety across runs: stale tags must mismatch)
  hipMemsetAsync(ws, 0, 65536 + 524288, stream);
  lstm_all<<<dim3(256), dim3(512), 0, stream>>>(p);
}